// Round 1
// baseline (6573.724 us; speedup 1.0000x reference)
//
#include <hip/hip_runtime.h>
#include <hip/hip_bf16.h>
#include <float.h>

#define NEG_SLOPE 0.01f

__device__ __forceinline__ float leaky(float x){ return x >= 0.0f ? x : NEG_SLOPE * x; }

// ---------------- transpose a batch of 64x64 matrices: [o][d] -> [d][o] ----------------
__global__ void k_transpose(const float* __restrict__ src, float* __restrict__ dst){
    int m = blockIdx.x;
    const float* s = src + (size_t)m * 4096;
    float* d = dst + (size_t)m * 4096;
    for (int t = threadIdx.x; t < 4096; t += blockDim.x){
        int o = t >> 6, dd = t & 63;
        d[dd * 64 + o] = s[t];
    }
}

// ---------------- first conv: 3 -> 64 ----------------
__global__ void k_conv0(const float* __restrict__ xyz, const float* __restrict__ w0,
                        float* __restrict__ out, int n){
    int t = blockIdx.x * blockDim.x + threadIdx.x;
    int nn = t % n;
    int rest = t / n;
    int o = rest & 63;
    int b = rest >> 6;
    const float* X = xyz + (size_t)b * 3 * n;
    float x = X[nn], y = X[n + nn], z = X[2 * n + nn];
    out[((size_t)b * 64 + o) * n + nn] = w0[o*3] * x + w0[o*3+1] * y + w0[o*3+2] * z;
}

// ---------------- kNN: for each query, indices of 8 nearest refs ----------------
#define KNN_CHUNK 1024
__global__ void k_knn(const float* __restrict__ q, const float* __restrict__ ref,
                      int M, int Nr, int* __restrict__ idx_out){
    __shared__ float4 sref[KNN_CHUNK];
    int b = blockIdx.y;
    int m = blockIdx.x * blockDim.x + threadIdx.x;
    const float* Q = q + (size_t)b * 3 * M;
    const float* R = ref + (size_t)b * 3 * Nr;
    bool valid = (m < M);
    float qx = 0.f, qy = 0.f, qz = 0.f, qq = 0.f;
    if (valid){
        qx = Q[m]; qy = Q[M + m]; qz = Q[2 * M + m];
        qq = qx*qx + qy*qy + qz*qz;
    }
    float bd[8]; int bi[8];
    #pragma unroll
    for (int i = 0; i < 8; ++i){ bd[i] = FLT_MAX; bi[i] = 0x7fffffff; }

    for (int base = 0; base < Nr; base += KNN_CHUNK){
        int jmax = min(KNN_CHUNK, Nr - base);
        __syncthreads();
        for (int j = threadIdx.x; j < jmax; j += blockDim.x){
            float rx = R[base + j], ry = R[Nr + base + j], rz = R[2 * Nr + base + j];
            sref[j] = make_float4(rx, ry, rz, rx*rx + ry*ry + rz*rz);
        }
        __syncthreads();
        if (valid){
            for (int j = 0; j < jmax; ++j){
                float4 r = sref[j];
                float dot = qx * r.x + qy * r.y + qz * r.z;
                float d = qq + r.w - 2.0f * dot;
                if (d < bd[7]){
                    // insert keeping ascending (d, idx); scanned ascending idx so
                    // strict '<' preserves lower-index-first on ties (matches lax.top_k)
                    float cd = d; int ci = base + j;
                    #pragma unroll
                    for (int t = 0; t < 8; ++t){
                        if (cd < bd[t]){
                            float td = bd[t]; int ti = bi[t];
                            bd[t] = cd; bi[t] = ci;
                            cd = td; ci = ti;
                        }
                    }
                }
            }
        }
    }
    if (valid){
        #pragma unroll
        for (int k = 0; k < 8; ++k) idx_out[((size_t)b * M + m) * 8 + k] = bi[k];
    }
}

// ---------------- farthest point sampling (one block per batch) ----------------
__global__ void k_fps(const float* __restrict__ xyz, int n, int npoint, int* __restrict__ sidx){
    int b = blockIdx.x;
    const float* X = xyz + (size_t)b * 3 * n;
    int T = blockDim.x;
    int tid = threadIdx.x;
    int P = n / T;  // 1..4, exact

    float cx[4], cy[4], cz[4], dist[4];
    #pragma unroll
    for (int p = 0; p < 4; ++p){
        if (p < P){
            int gi = tid + p * T;
            cx[p] = X[gi]; cy[p] = X[n + gi]; cz[p] = X[2 * n + gi];
            dist[p] = 1e10f;
        }
    }
    __shared__ float rv[16];
    __shared__ int ri[16];
    __shared__ int s_last;
    int nw = T >> 6;
    int last = 0;
    if (tid == 0) sidx[(size_t)b * npoint] = 0;

    for (int i = 1; i < npoint; ++i){
        float lx = X[last], ly = X[n + last], lz = X[2 * n + last];
        float best = -1.0f; int bidx = 0x7fffffff;
        #pragma unroll
        for (int p = 0; p < 4; ++p){
            if (p < P){
                float dx = cx[p] - lx, dy = cy[p] - ly, dz = cz[p] - lz;
                float d = dx*dx + dy*dy + dz*dz;
                float nd = fminf(dist[p], d);
                dist[p] = nd;
                int gi = tid + p * T;
                if (nd > best || (nd == best && gi < bidx)){ best = nd; bidx = gi; }
            }
        }
        #pragma unroll
        for (int off = 32; off; off >>= 1){
            float ov = __shfl_xor(best, off);
            int oi = __shfl_xor(bidx, off);
            if (ov > best || (ov == best && oi < bidx)){ best = ov; bidx = oi; }
        }
        if ((tid & 63) == 0){ rv[tid >> 6] = best; ri[tid >> 6] = bidx; }
        __syncthreads();
        if (tid == 0){
            float wv = rv[0]; int wi = ri[0];
            for (int w = 1; w < nw; ++w){
                if (rv[w] > wv || (rv[w] == wv && ri[w] < wi)){ wv = rv[w]; wi = ri[w]; }
            }
            s_last = wi;
            sidx[(size_t)b * npoint + i] = wi;
        }
        __syncthreads();
        last = s_last;
    }
}

// ---------------- gather sampled xyz ----------------
__global__ void k_gather_xyz(const float* __restrict__ xyz, const int* __restrict__ sidx,
                             float* __restrict__ out, int n, int np){
    int t = blockIdx.x * blockDim.x + threadIdx.x;
    if (t >= 8 * 3 * np) return;
    int m = t % np;
    int c = (t / np) % 3;
    int b = t / (3 * np);
    out[((size_t)b * 3 + c) * np + m] = xyz[((size_t)b * 3 + c) * n + sidx[(size_t)b * np + m]];
}

// ---------------- max-pool over k grouped neighbors ----------------
__global__ void k_pool_max(const float* __restrict__ src, const int* __restrict__ idx,
                           float* __restrict__ out, int np, int nsrc){
    int m = blockIdx.x * blockDim.x + threadIdx.x;
    if (m >= np) return;
    int d = blockIdx.y, b = blockIdx.z;
    const float* row = src + ((size_t)b * 64 + d) * nsrc;
    const int* id = idx + ((size_t)b * np + m) * 8;
    float v = -FLT_MAX;
    #pragma unroll
    for (int k = 0; k < 8; ++k) v = fmaxf(v, row[id[k]]);
    out[((size_t)b * 64 + d) * np + m] = v;
}

// ---------------- neighbor sum of leaky(points) ----------------
__global__ void k_gather_sum(const float* __restrict__ src, const int* __restrict__ idx,
                             float* __restrict__ out, int n){
    int m = blockIdx.x * blockDim.x + threadIdx.x;
    if (m >= n) return;
    int d = blockIdx.y, b = blockIdx.z;
    const float* row = src + ((size_t)b * 64 + d) * n;
    const int* id = idx + ((size_t)b * n + m) * 8;
    float v = 0.f;
    #pragma unroll
    for (int k = 0; k < 8; ++k) v += leaky(row[id[k]]);
    out[((size_t)b * 64 + d) * n + m] = v;
}

// ---------------- dual GEMM + epilogue: out = (wc@leaky(P) + wg@S)/9 + P ----------------
__global__ void k_res_conv(const float* __restrict__ pts, const float* __restrict__ s,
                           const float* __restrict__ wcT, const float* __restrict__ wgT,
                           float* __restrict__ out, int n){
    int j = blockIdx.x * blockDim.x + threadIdx.x;
    if (j >= n) return;
    int b = blockIdx.y;
    const float* P = pts + (size_t)b * 64 * n;
    const float* S = s + (size_t)b * 64 * n;
    float acc[64];
    #pragma unroll
    for (int o = 0; o < 64; ++o) acc[o] = 0.f;
    for (int d = 0; d < 64; ++d){
        float h = leaky(P[(size_t)d * n + j]);
        float sv = S[(size_t)d * n + j];
        const float* wc = wcT + d * 64;  // uniform addresses -> s_load
        const float* wg = wgT + d * 64;
        #pragma unroll
        for (int o = 0; o < 64; ++o) acc[o] = fmaf(wc[o], h, fmaf(wg[o], sv, acc[o]));
    }
    const float inv = 1.0f / 9.0f;
    #pragma unroll
    for (int o = 0; o < 64; ++o)
        out[((size_t)b * 64 + o) * n + j] = acc[o] * inv + P[(size_t)o * n + j];
}

// ---------------- last layer: leaky -> 1x1 conv to 1 channel ----------------
__global__ void k_final(const float* __restrict__ pts, const float* __restrict__ wl,
                        float* __restrict__ out){
    int t = blockIdx.x * blockDim.x + threadIdx.x;
    if (t >= 512) return;
    int b = t >> 6, m = t & 63;
    const float* P = pts + (size_t)b * 64 * 64;
    float acc = 0.f;
    for (int d = 0; d < 64; ++d) acc += wl[d] * leaky(P[d * 64 + m]);
    out[t] = acc;
}

extern "C" void kernel_launch(void* const* d_in, const int* in_sizes, int n_in,
                              void* d_out, int out_size, void* d_ws, size_t ws_size,
                              hipStream_t stream){
    const float* xyz_in  = (const float*)d_in[0];
    const float* w0      = (const float*)d_in[1];
    const float* fn_wc   = (const float*)d_in[2];
    const float* fn_wg   = (const float*)d_in[3];
    const float* res_wc  = (const float*)d_in[4];
    const float* res_wg  = (const float*)d_in[5];
    const float* w_last  = (const float*)d_in[6];
    float* out = (float*)d_out;

    char* ws = (char*)d_ws;
    size_t off = 0;
    auto alloc = [&](size_t bytes) -> char* {
        char* p = ws + off;
        off = (off + bytes + 255) & ~(size_t)255;
        return p;
    };
    float* wT_fnc = (float*)alloc(2UL  * 4096 * 4);
    float* wT_fng = (float*)alloc(2UL  * 4096 * 4);
    float* wT_rc  = (float*)alloc(12UL * 4096 * 4);
    float* wT_rg  = (float*)alloc(12UL * 4096 * 4);
    float* pts_a  = (float*)alloc(8UL * 64 * 4096 * 4);
    float* pts_b  = (float*)alloc(8UL * 64 * 4096 * 4);
    float* s_buf  = (float*)alloc(8UL * 64 * 4096 * 4);
    int*   idx_b  = (int*)  alloc(8UL * 4096 * 8 * 4);
    float* xyz1   = (float*)alloc(8UL * 3 * 1024 * 4);
    float* xyz2   = (float*)alloc(8UL * 3 * 1024 * 4);
    int*   sidx   = (int*)  alloc(8UL * 1024 * 4);

    // transpose all weight matrices to [d][o]
    k_transpose<<<2,  256, 0, stream>>>(fn_wc,  wT_fnc);
    k_transpose<<<2,  256, 0, stream>>>(fn_wg,  wT_fng);
    k_transpose<<<12, 256, 0, stream>>>(res_wc, wT_rc);
    k_transpose<<<12, 256, 0, stream>>>(res_wg, wT_rg);

    int n = 4096;
    k_conv0<<<(8 * 64 * n) / 256, 256, 0, stream>>>(xyz_in, w0, pts_a, n);

    const float* cxyz = xyz_in;
    {
        dim3 kb((n + 255) / 256, 8);
        k_knn<<<kb, 256, 0, stream>>>(cxyz, cxyz, n, n, idx_b);
    }
    float* pc = pts_a;
    float* pn = pts_b;
    for (int j = 0; j < 2; ++j){
        dim3 g((n + 255) / 256, 64, 8);
        k_gather_sum<<<g, 256, 0, stream>>>(pc, idx_b, s_buf, n);
        dim3 g2((n + 255) / 256, 8);
        k_res_conv<<<g2, 256, 0, stream>>>(pc, s_buf, wT_fnc + j * 4096, wT_fng + j * 4096, pn, n);
        float* t = pc; pc = pn; pn = t;
    }

    float* xyzbufs[2] = {xyz1, xyz2};
    for (int l = 0; l < 3; ++l){
        int np = n / 4;
        int fT = (n >= 1024) ? 1024 : n;   // n = 4096,1024,256
        k_fps<<<8, fT, 0, stream>>>(cxyz, n, np, sidx);

        float* nxyz = xyzbufs[l & 1];
        int tot = 8 * 3 * np;
        k_gather_xyz<<<(tot + 255) / 256, 256, 0, stream>>>(cxyz, sidx, nxyz, n, np);

        dim3 kg((np + 255) / 256, 8);
        k_knn<<<kg, 256, 0, stream>>>(nxyz, cxyz, np, n, idx_b);

        dim3 pm((np + 255) / 256, 64, 8);
        k_pool_max<<<pm, 256, 0, stream>>>(pc, idx_b, pn, np, n);
        float* t = pc; pc = pn; pn = t;

        cxyz = nxyz; n = np;

        dim3 ks((n + 255) / 256, 8);
        k_knn<<<ks, 256, 0, stream>>>(cxyz, cxyz, n, n, idx_b);

        for (int i = 0; i < 4; ++i){
            dim3 g((n + 255) / 256, 64, 8);
            k_gather_sum<<<g, 256, 0, stream>>>(pc, idx_b, s_buf, n);
            dim3 g2((n + 255) / 256, 8);
            k_res_conv<<<g2, 256, 0, stream>>>(pc, s_buf, wT_rc + (l * 4 + i) * 4096,
                                               wT_rg + (l * 4 + i) * 4096, pn, n);
            t = pc; pc = pn; pn = t;
        }
    }

    k_final<<<2, 256, 0, stream>>>(pc, w_last, out);
}

// Round 2
// 4022.555 us; speedup vs baseline: 1.6342x; 1.6342x over previous
//
#include <hip/hip_runtime.h>
#include <hip/hip_bf16.h>
#include <float.h>

#define NEG_SLOPE 0.01f

__device__ __forceinline__ float leaky(float x){ return x >= 0.0f ? x : NEG_SLOPE * x; }

// ---------------- transpose a batch of 64x64 matrices: [o][d] -> [d][o] ----------------
__global__ void k_transpose(const float* __restrict__ src, float* __restrict__ dst){
    int m = blockIdx.x;
    const float* s = src + (size_t)m * 4096;
    float* d = dst + (size_t)m * 4096;
    for (int t = threadIdx.x; t < 4096; t += blockDim.x){
        int o = t >> 6, dd = t & 63;
        d[dd * 64 + o] = s[t];
    }
}

// ---------------- first conv: 3 -> 64 ----------------
__global__ void k_conv0(const float* __restrict__ xyz, const float* __restrict__ w0,
                        float* __restrict__ out, int n){
    int t = blockIdx.x * blockDim.x + threadIdx.x;
    int nn = t % n;
    int rest = t / n;
    int o = rest & 63;
    int b = rest >> 6;
    const float* X = xyz + (size_t)b * 3 * n;
    float x = X[nn], y = X[n + nn], z = X[2 * n + nn];
    out[((size_t)b * 64 + o) * n + nn] = w0[o*3] * x + w0[o*3+1] * y + w0[o*3+2] * z;
}

// ---------------- kNN: for each query, indices of 8 nearest refs ----------------
// Top-8 kept in NAMED registers (manual scalarization -- array form was demoted
// to scratch: VGPR_Count=24 observed, needs ~40). Branchless compare-swap chain.
#define KNN_CHUNK 1024
#define BKNN 64

#define KNN_INS(bdX, biX) { bool c = cd < bdX; float tf = bdX; int ti = biX; \
    bdX = c ? cd : bdX; biX = c ? ci : biX; cd = c ? tf : cd; ci = c ? ti : ci; }

__global__ void k_knn(const float* __restrict__ q, const float* __restrict__ ref,
                      int M, int Nr, int* __restrict__ idx_out){
    __shared__ float4 sref[KNN_CHUNK];
    int b = blockIdx.y;
    int m = blockIdx.x * BKNN + threadIdx.x;
    const float* Q = q + (size_t)b * 3 * M;
    const float* R = ref + (size_t)b * 3 * Nr;
    bool valid = (m < M);
    float qx = 0.f, qy = 0.f, qz = 0.f, qq = 0.f;
    if (valid){
        qx = Q[m]; qy = Q[M + m]; qz = Q[2 * M + m];
        qq = qx*qx + qy*qy + qz*qz;
    }
    float bd0 = FLT_MAX, bd1 = FLT_MAX, bd2 = FLT_MAX, bd3 = FLT_MAX;
    float bd4 = FLT_MAX, bd5 = FLT_MAX, bd6 = FLT_MAX, bd7 = FLT_MAX;
    int bi0 = 0, bi1 = 0, bi2 = 0, bi3 = 0, bi4 = 0, bi5 = 0, bi6 = 0, bi7 = 0;

    for (int base = 0; base < Nr; base += KNN_CHUNK){
        int jmax = min(KNN_CHUNK, Nr - base);
        for (int j = threadIdx.x; j < jmax; j += BKNN){
            float rx = R[base + j], ry = R[Nr + base + j], rz = R[2 * Nr + base + j];
            sref[j] = make_float4(rx, ry, rz, rx*rx + ry*ry + rz*rz);
        }
        __syncthreads();
        for (int j = 0; j < jmax; ++j){
            float4 r = sref[j];
            float dot = qx * r.x + qy * r.y + qz * r.z;
            float d = qq + r.w - 2.0f * dot;
            if (d < bd7){
                // insert keeping ascending (d, idx); scanned ascending idx so
                // strict '<' preserves lower-index-first on ties (matches lax.top_k)
                float cd = d; int ci = base + j;
                KNN_INS(bd0, bi0); KNN_INS(bd1, bi1); KNN_INS(bd2, bi2); KNN_INS(bd3, bi3);
                KNN_INS(bd4, bi4); KNN_INS(bd5, bi5); KNN_INS(bd6, bi6); KNN_INS(bd7, bi7);
            }
        }
        __syncthreads();
    }
    if (valid){
        int* o = idx_out + ((size_t)b * M + m) * 8;
        o[0] = bi0; o[1] = bi1; o[2] = bi2; o[3] = bi3;
        o[4] = bi4; o[5] = bi5; o[6] = bi6; o[7] = bi7;
    }
}

// ---------------- farthest point sampling (one block of 256 per batch) ----------------
// Compile-time P (points per thread) so the state arrays fully promote to VGPRs.
// (dist,idx,x,y,z) tuple carried through the reduction -> no global gather of the
// winner's coords; double-buffered LDS -> ONE barrier per iteration; every thread
// resolves the cross-wave winner itself (no serial tid-0 scan / broadcast).
template<int P>
__global__ void k_fps(const float* __restrict__ xyz, int n, int npoint, int* __restrict__ sidx){
    const int T = 256;
    int b = blockIdx.x;
    const float* X = xyz + (size_t)b * 3 * n;
    int tid = threadIdx.x;

    float px[P], py[P], pz[P], dist[P];
    #pragma unroll
    for (int p = 0; p < P; ++p){
        int gi = tid + p * T;
        px[p] = X[gi]; py[p] = X[n + gi]; pz[p] = X[2 * n + gi];
        dist[p] = 1e10f;
    }
    __shared__ float4 sbest[2][4];
    __shared__ int    sbidx[2][4];
    if (tid == 0) sidx[(size_t)b * npoint] = 0;
    // coords of current sample (point 0): uniform addresses -> scalar loads
    float lx = X[0], ly = X[n], lz = X[2 * n];

    for (int i = 1; i < npoint; ++i){
        float best = -1.0f; int bidx = 0;
        float bx = 0.f, by = 0.f, bz = 0.f;
        #pragma unroll
        for (int p = 0; p < P; ++p){
            float dx = px[p] - lx, dy = py[p] - ly, dz = pz[p] - lz;
            float d = dx*dx + dy*dy + dz*dz;
            float nd = fminf(dist[p], d);
            dist[p] = nd;
            bool c = (nd > best);   // ascending gi scan; strict '>' keeps lowest gi on ties
            best = c ? nd : best;
            bidx = c ? (tid + p * T) : bidx;
            bx = c ? px[p] : bx; by = c ? py[p] : by; bz = c ? pz[p] : bz;
        }
        #pragma unroll
        for (int off = 32; off; off >>= 1){
            float od = __shfl_xor(best, off);
            int   oi = __shfl_xor(bidx, off);
            float ox = __shfl_xor(bx, off);
            float oy = __shfl_xor(by, off);
            float oz = __shfl_xor(bz, off);
            bool c = (od > best) || (od == best && oi < bidx);
            best = c ? od : best; bidx = c ? oi : bidx;
            bx = c ? ox : bx; by = c ? oy : by; bz = c ? oz : bz;
        }
        int buf = i & 1;
        if ((tid & 63) == 0){
            sbest[buf][tid >> 6] = make_float4(bx, by, bz, best);
            sbidx[buf][tid >> 6] = bidx;
        }
        __syncthreads();
        float4 t0 = sbest[buf][0]; int i0 = sbidx[buf][0];
        #pragma unroll
        for (int w = 1; w < 4; ++w){
            float4 tw = sbest[buf][w]; int iw = sbidx[buf][w];
            bool c = (tw.w > t0.w) || (tw.w == t0.w && iw < i0);
            t0.x = c ? tw.x : t0.x; t0.y = c ? tw.y : t0.y;
            t0.z = c ? tw.z : t0.z; t0.w = c ? tw.w : t0.w;
            i0 = c ? iw : i0;
        }
        lx = t0.x; ly = t0.y; lz = t0.z;
        if (tid == 0) sidx[(size_t)b * npoint + i] = i0;
    }
}

// ---------------- gather sampled xyz ----------------
__global__ void k_gather_xyz(const float* __restrict__ xyz, const int* __restrict__ sidx,
                             float* __restrict__ out, int n, int np){
    int t = blockIdx.x * blockDim.x + threadIdx.x;
    if (t >= 8 * 3 * np) return;
    int m = t % np;
    int c = (t / np) % 3;
    int b = t / (3 * np);
    out[((size_t)b * 3 + c) * np + m] = xyz[((size_t)b * 3 + c) * n + sidx[(size_t)b * np + m]];
}

// ---------------- max-pool over k grouped neighbors ----------------
__global__ void k_pool_max(const float* __restrict__ src, const int* __restrict__ idx,
                           float* __restrict__ out, int np, int nsrc){
    int m = blockIdx.x * blockDim.x + threadIdx.x;
    if (m >= np) return;
    int d = blockIdx.y, b = blockIdx.z;
    const float* row = src + ((size_t)b * 64 + d) * nsrc;
    const int* id = idx + ((size_t)b * np + m) * 8;
    float v = -FLT_MAX;
    #pragma unroll
    for (int k = 0; k < 8; ++k) v = fmaxf(v, row[id[k]]);
    out[((size_t)b * 64 + d) * np + m] = v;
}

// ---------------- neighbor sum of leaky(points) ----------------
__global__ void k_gather_sum(const float* __restrict__ src, const int* __restrict__ idx,
                             float* __restrict__ out, int n){
    int m = blockIdx.x * blockDim.x + threadIdx.x;
    if (m >= n) return;
    int d = blockIdx.y, b = blockIdx.z;
    const float* row = src + ((size_t)b * 64 + d) * n;
    const int* id = idx + ((size_t)b * n + m) * 8;
    float v = 0.f;
    #pragma unroll
    for (int k = 0; k < 8; ++k) v += leaky(row[id[k]]);
    out[((size_t)b * 64 + d) * n + m] = v;
}

// ---------------- dual GEMM + epilogue: out = (wc@leaky(P) + wg@S)/9 + P ----------------
__global__ void k_res_conv(const float* __restrict__ pts, const float* __restrict__ s,
                           const float* __restrict__ wcT, const float* __restrict__ wgT,
                           float* __restrict__ out, int n){
    int j = blockIdx.x * blockDim.x + threadIdx.x;
    if (j >= n) return;
    int b = blockIdx.y;
    const float* P = pts + (size_t)b * 64 * n;
    const float* S = s + (size_t)b * 64 * n;
    float acc[64];
    #pragma unroll
    for (int o = 0; o < 64; ++o) acc[o] = 0.f;
    for (int d = 0; d < 64; ++d){
        float h = leaky(P[(size_t)d * n + j]);
        float sv = S[(size_t)d * n + j];
        const float* wc = wcT + d * 64;  // uniform addresses -> s_load
        const float* wg = wgT + d * 64;
        #pragma unroll
        for (int o = 0; o < 64; ++o) acc[o] = fmaf(wc[o], h, fmaf(wg[o], sv, acc[o]));
    }
    const float inv = 1.0f / 9.0f;
    #pragma unroll
    for (int o = 0; o < 64; ++o)
        out[((size_t)b * 64 + o) * n + j] = acc[o] * inv + P[(size_t)o * n + j];
}

// ---------------- last layer: leaky -> 1x1 conv to 1 channel ----------------
__global__ void k_final(const float* __restrict__ pts, const float* __restrict__ wl,
                        float* __restrict__ out){
    int t = blockIdx.x * blockDim.x + threadIdx.x;
    if (t >= 512) return;
    int b = t >> 6, m = t & 63;
    const float* P = pts + (size_t)b * 64 * 64;
    float acc = 0.f;
    for (int d = 0; d < 64; ++d) acc += wl[d] * leaky(P[d * 64 + m]);
    out[t] = acc;
}

extern "C" void kernel_launch(void* const* d_in, const int* in_sizes, int n_in,
                              void* d_out, int out_size, void* d_ws, size_t ws_size,
                              hipStream_t stream){
    const float* xyz_in  = (const float*)d_in[0];
    const float* w0      = (const float*)d_in[1];
    const float* fn_wc   = (const float*)d_in[2];
    const float* fn_wg   = (const float*)d_in[3];
    const float* res_wc  = (const float*)d_in[4];
    const float* res_wg  = (const float*)d_in[5];
    const float* w_last  = (const float*)d_in[6];
    float* out = (float*)d_out;

    char* ws = (char*)d_ws;
    size_t off = 0;
    auto alloc = [&](size_t bytes) -> char* {
        char* p = ws + off;
        off = (off + bytes + 255) & ~(size_t)255;
        return p;
    };
    float* wT_fnc = (float*)alloc(2UL  * 4096 * 4);
    float* wT_fng = (float*)alloc(2UL  * 4096 * 4);
    float* wT_rc  = (float*)alloc(12UL * 4096 * 4);
    float* wT_rg  = (float*)alloc(12UL * 4096 * 4);
    float* pts_a  = (float*)alloc(8UL * 64 * 4096 * 4);
    float* pts_b  = (float*)alloc(8UL * 64 * 4096 * 4);
    float* s_buf  = (float*)alloc(8UL * 64 * 4096 * 4);
    int*   idx_b  = (int*)  alloc(8UL * 4096 * 8 * 4);
    float* xyz1   = (float*)alloc(8UL * 3 * 1024 * 4);
    float* xyz2   = (float*)alloc(8UL * 3 * 1024 * 4);
    int*   sidx   = (int*)  alloc(8UL * 1024 * 4);

    // transpose all weight matrices to [d][o]
    k_transpose<<<2,  256, 0, stream>>>(fn_wc,  wT_fnc);
    k_transpose<<<2,  256, 0, stream>>>(fn_wg,  wT_fng);
    k_transpose<<<12, 256, 0, stream>>>(res_wc, wT_rc);
    k_transpose<<<12, 256, 0, stream>>>(res_wg, wT_rg);

    int n = 4096;
    k_conv0<<<(8 * 64 * n) / 256, 256, 0, stream>>>(xyz_in, w0, pts_a, n);

    const float* cxyz = xyz_in;
    {
        dim3 kb((n + BKNN - 1) / BKNN, 8);
        k_knn<<<kb, BKNN, 0, stream>>>(cxyz, cxyz, n, n, idx_b);
    }
    float* pc = pts_a;
    float* pn = pts_b;
    for (int j = 0; j < 2; ++j){
        dim3 g((n + 255) / 256, 64, 8);
        k_gather_sum<<<g, 256, 0, stream>>>(pc, idx_b, s_buf, n);
        dim3 g2((n + 255) / 256, 8);
        k_res_conv<<<g2, 256, 0, stream>>>(pc, s_buf, wT_fnc + j * 4096, wT_fng + j * 4096, pn, n);
        float* t = pc; pc = pn; pn = t;
    }

    float* xyzbufs[2] = {xyz1, xyz2};
    for (int l = 0; l < 3; ++l){
        int np = n / 4;
        if (n == 4096)      k_fps<16><<<8, 256, 0, stream>>>(cxyz, n, np, sidx);
        else if (n == 1024) k_fps<4><<<8, 256, 0, stream>>>(cxyz, n, np, sidx);
        else                k_fps<1><<<8, 256, 0, stream>>>(cxyz, n, np, sidx);

        float* nxyz = xyzbufs[l & 1];
        int tot = 8 * 3 * np;
        k_gather_xyz<<<(tot + 255) / 256, 256, 0, stream>>>(cxyz, sidx, nxyz, n, np);

        dim3 kg((np + BKNN - 1) / BKNN, 8);
        k_knn<<<kg, BKNN, 0, stream>>>(nxyz, cxyz, np, n, idx_b);

        dim3 pm((np + 255) / 256, 64, 8);
        k_pool_max<<<pm, 256, 0, stream>>>(pc, idx_b, pn, np, n);
        float* t = pc; pc = pn; pn = t;

        cxyz = nxyz; n = np;

        dim3 ks((n + BKNN - 1) / BKNN, 8);
        k_knn<<<ks, BKNN, 0, stream>>>(cxyz, cxyz, n, n, idx_b);

        for (int i = 0; i < 4; ++i){
            dim3 g((n + 255) / 256, 64, 8);
            k_gather_sum<<<g, 256, 0, stream>>>(pc, idx_b, s_buf, n);
            dim3 g2((n + 255) / 256, 8);
            k_res_conv<<<g2, 256, 0, stream>>>(pc, s_buf, wT_rc + (l * 4 + i) * 4096,
                                               wT_rg + (l * 4 + i) * 4096, pn, n);
            t = pc; pc = pn; pn = t;
        }
    }

    k_final<<<2, 256, 0, stream>>>(pc, w_last, out);
}

// Round 3
// 3989.082 us; speedup vs baseline: 1.6479x; 1.0084x over previous
//
#include <hip/hip_runtime.h>
#include <hip/hip_bf16.h>
#include <float.h>

#define NEG_SLOPE 0.01f

__device__ __forceinline__ float leaky(float x){ return x >= 0.0f ? x : NEG_SLOPE * x; }

// ---------------- transpose a batch of 64x64 matrices: [o][d] -> [d][o] ----------------
__global__ void k_transpose(const float* __restrict__ src, float* __restrict__ dst){
    int m = blockIdx.x;
    const float* s = src + (size_t)m * 4096;
    float* d = dst + (size_t)m * 4096;
    for (int t = threadIdx.x; t < 4096; t += blockDim.x){
        int o = t >> 6, dd = t & 63;
        d[dd * 64 + o] = s[t];
    }
}

// ---------------- first conv: 3 -> 64 ----------------
__global__ void k_conv0(const float* __restrict__ xyz, const float* __restrict__ w0,
                        float* __restrict__ out, int n){
    int t = blockIdx.x * blockDim.x + threadIdx.x;
    int nn = t % n;
    int rest = t / n;
    int o = rest & 63;
    int b = rest >> 6;
    const float* X = xyz + (size_t)b * 3 * n;
    float x = X[nn], y = X[n + nn], z = X[2 * n + nn];
    out[((size_t)b * 64 + o) * n + nn] = w0[o*3] * x + w0[o*3+1] * y + w0[o*3+2] * z;
}

// ---------------- kNN: for each query, indices of 8 nearest refs ----------------
// Top-8 kept in NAMED registers; branchless compare-swap insertion chain.
#define KNN_CHUNK 1024
#define BKNN 64

#define KNN_INS(bdX, biX) { bool c = cd < bdX; float tf = bdX; int ti = biX; \
    bdX = c ? cd : bdX; biX = c ? ci : biX; cd = c ? tf : cd; ci = c ? ti : ci; }

__global__ void __launch_bounds__(BKNN, 1)
k_knn(const float* __restrict__ q, const float* __restrict__ ref,
      int M, int Nr, int* __restrict__ idx_out){
    __shared__ float4 sref[KNN_CHUNK];
    int b = blockIdx.y;
    int m = blockIdx.x * BKNN + threadIdx.x;
    const float* Q = q + (size_t)b * 3 * M;
    const float* R = ref + (size_t)b * 3 * Nr;
    bool valid = (m < M);
    float qx = 0.f, qy = 0.f, qz = 0.f, qq = 0.f;
    if (valid){
        qx = Q[m]; qy = Q[M + m]; qz = Q[2 * M + m];
        qq = qx*qx + qy*qy + qz*qz;
    }
    float bd0 = FLT_MAX, bd1 = FLT_MAX, bd2 = FLT_MAX, bd3 = FLT_MAX;
    float bd4 = FLT_MAX, bd5 = FLT_MAX, bd6 = FLT_MAX, bd7 = FLT_MAX;
    int bi0 = 0, bi1 = 0, bi2 = 0, bi3 = 0, bi4 = 0, bi5 = 0, bi6 = 0, bi7 = 0;

    for (int base = 0; base < Nr; base += KNN_CHUNK){
        int jmax = min(KNN_CHUNK, Nr - base);
        for (int j = threadIdx.x; j < jmax; j += BKNN){
            float rx = R[base + j], ry = R[Nr + base + j], rz = R[2 * Nr + base + j];
            sref[j] = make_float4(rx, ry, rz, rx*rx + ry*ry + rz*rz);
        }
        __syncthreads();
        for (int j = 0; j < jmax; ++j){
            float4 r = sref[j];
            float dot = qx * r.x + qy * r.y + qz * r.z;
            float d = qq + r.w - 2.0f * dot;
            if (d < bd7){
                // ascending-index scan + strict '<' => lowest index wins ties (matches lax.top_k)
                float cd = d; int ci = base + j;
                KNN_INS(bd0, bi0); KNN_INS(bd1, bi1); KNN_INS(bd2, bi2); KNN_INS(bd3, bi3);
                KNN_INS(bd4, bi4); KNN_INS(bd5, bi5); KNN_INS(bd6, bi6); KNN_INS(bd7, bi7);
            }
        }
        __syncthreads();
    }
    if (valid){
        int* o = idx_out + ((size_t)b * M + m) * 8;
        o[0] = bi0; o[1] = bi1; o[2] = bi2; o[3] = bi3;
        o[4] = bi4; o[5] = bi5; o[6] = bi6; o[7] = bi7;
    }
}

// ---------------- farthest point sampling (one block of 256 per batch) ----------------
// Per-point state in NAMED scalar registers (macro-expanded: template arrays were
// demoted to scratch — VGPR_Count=56 < 64 live floats). __launch_bounds__(256,1)
// lifts the VGPR budget (one block per CU; occupancy irrelevant).
#define FPS_DECL(i) float px##i, py##i, pz##i, ds##i;
#define FPS_LOAD(i) { int gi = tid + (i) * 256; px##i = X[gi]; py##i = X[n + gi]; \
                      pz##i = X[2 * n + gi]; ds##i = 1e10f; }
#define FPS_UPD(i) { float dx = px##i - lx, dy = py##i - ly, dz = pz##i - lz; \
    float d = dx*dx + dy*dy + dz*dz; \
    float nd = fminf(ds##i, d); ds##i = nd; \
    bool c = (nd > best); \
    best = c ? nd : best; bidx = c ? (tid + (i) * 256) : bidx; \
    bx = c ? px##i : bx; by = c ? py##i : by; bz = c ? pz##i : bz; }

#define RPT16(M) M(0) M(1) M(2) M(3) M(4) M(5) M(6) M(7) \
                 M(8) M(9) M(10) M(11) M(12) M(13) M(14) M(15)
#define RPT4(M) M(0) M(1) M(2) M(3)
#define RPT1(M) M(0)

#define FPS_BODY(RPT) \
    const int b = blockIdx.x; \
    const float* X = xyz + (size_t)b * 3 * n; \
    int tid = threadIdx.x; \
    RPT(FPS_DECL) \
    RPT(FPS_LOAD) \
    __shared__ float4 sbest[2][4]; \
    __shared__ int    sbidx[2][4]; \
    if (tid == 0) sidx[(size_t)b * npoint] = 0; \
    float lx = X[0], ly = X[n], lz = X[2 * n]; \
    for (int i = 1; i < npoint; ++i){ \
        float best = -1.0f; int bidx = 0; \
        float bx = 0.f, by = 0.f, bz = 0.f; \
        RPT(FPS_UPD) \
        _Pragma("unroll") \
        for (int off = 32; off; off >>= 1){ \
            float od = __shfl_xor(best, off); \
            int   oi = __shfl_xor(bidx, off); \
            float ox = __shfl_xor(bx, off); \
            float oy = __shfl_xor(by, off); \
            float oz = __shfl_xor(bz, off); \
            bool c = (od > best) || (od == best && oi < bidx); \
            best = c ? od : best; bidx = c ? oi : bidx; \
            bx = c ? ox : bx; by = c ? oy : by; bz = c ? oz : bz; \
        } \
        int buf = i & 1; \
        if ((tid & 63) == 0){ \
            sbest[buf][tid >> 6] = make_float4(bx, by, bz, best); \
            sbidx[buf][tid >> 6] = bidx; \
        } \
        __syncthreads(); \
        float4 t0 = sbest[buf][0]; int i0 = sbidx[buf][0]; \
        _Pragma("unroll") \
        for (int w = 1; w < 4; ++w){ \
            float4 tw = sbest[buf][w]; int iw = sbidx[buf][w]; \
            bool c = (tw.w > t0.w) || (tw.w == t0.w && iw < i0); \
            t0.x = c ? tw.x : t0.x; t0.y = c ? tw.y : t0.y; \
            t0.z = c ? tw.z : t0.z; t0.w = c ? tw.w : t0.w; \
            i0 = c ? iw : i0; \
        } \
        lx = t0.x; ly = t0.y; lz = t0.z; \
        if (tid == 0) sidx[(size_t)b * npoint + i] = i0; \
    }

__global__ void __launch_bounds__(256, 1)
k_fps16(const float* __restrict__ xyz, int n, int npoint, int* __restrict__ sidx){
    FPS_BODY(RPT16)
}
__global__ void __launch_bounds__(256, 1)
k_fps4(const float* __restrict__ xyz, int n, int npoint, int* __restrict__ sidx){
    FPS_BODY(RPT4)
}
__global__ void __launch_bounds__(256, 1)
k_fps1(const float* __restrict__ xyz, int n, int npoint, int* __restrict__ sidx){
    FPS_BODY(RPT1)
}

// ---------------- gather sampled xyz ----------------
__global__ void k_gather_xyz(const float* __restrict__ xyz, const int* __restrict__ sidx,
                             float* __restrict__ out, int n, int np){
    int t = blockIdx.x * blockDim.x + threadIdx.x;
    if (t >= 8 * 3 * np) return;
    int m = t % np;
    int c = (t / np) % 3;
    int b = t / (3 * np);
    out[((size_t)b * 3 + c) * np + m] = xyz[((size_t)b * 3 + c) * n + sidx[(size_t)b * np + m]];
}

// ---------------- max-pool over k grouped neighbors ----------------
__global__ void k_pool_max(const float* __restrict__ src, const int* __restrict__ idx,
                           float* __restrict__ out, int np, int nsrc){
    int m = blockIdx.x * blockDim.x + threadIdx.x;
    if (m >= np) return;
    int d = blockIdx.y, b = blockIdx.z;
    const float* row = src + ((size_t)b * 64 + d) * nsrc;
    const int* id = idx + ((size_t)b * np + m) * 8;
    float v = -FLT_MAX;
    #pragma unroll
    for (int k = 0; k < 8; ++k) v = fmaxf(v, row[id[k]]);
    out[((size_t)b * 64 + d) * np + m] = v;
}

// ---------------- neighbor sum of leaky(points) ----------------
__global__ void k_gather_sum(const float* __restrict__ src, const int* __restrict__ idx,
                             float* __restrict__ out, int n){
    int m = blockIdx.x * blockDim.x + threadIdx.x;
    if (m >= n) return;
    int d = blockIdx.y, b = blockIdx.z;
    const float* row = src + ((size_t)b * 64 + d) * n;
    const int* id = idx + ((size_t)b * n + m) * 8;
    float v = 0.f;
    #pragma unroll
    for (int k = 0; k < 8; ++k) v += leaky(row[id[k]]);
    out[((size_t)b * 64 + d) * n + m] = v;
}

// ---------------- dual GEMM + epilogue: out = (wc@leaky(P) + wg@S)/9 + P ----------------
__global__ void __launch_bounds__(256, 1)
k_res_conv(const float* __restrict__ pts, const float* __restrict__ s,
           const float* __restrict__ wcT, const float* __restrict__ wgT,
           float* __restrict__ out, int n){
    int j = blockIdx.x * blockDim.x + threadIdx.x;
    if (j >= n) return;
    int b = blockIdx.y;
    const float* P = pts + (size_t)b * 64 * n;
    const float* S = s + (size_t)b * 64 * n;
    float acc[64];
    #pragma unroll
    for (int o = 0; o < 64; ++o) acc[o] = 0.f;
    for (int d = 0; d < 64; ++d){
        float h = leaky(P[(size_t)d * n + j]);
        float sv = S[(size_t)d * n + j];
        const float* wc = wcT + d * 64;  // uniform addresses -> s_load
        const float* wg = wgT + d * 64;
        #pragma unroll
        for (int o = 0; o < 64; ++o) acc[o] = fmaf(wc[o], h, fmaf(wg[o], sv, acc[o]));
    }
    const float inv = 1.0f / 9.0f;
    #pragma unroll
    for (int o = 0; o < 64; ++o)
        out[((size_t)b * 64 + o) * n + j] = acc[o] * inv + P[(size_t)o * n + j];
}

// ---------------- last layer: leaky -> 1x1 conv to 1 channel ----------------
__global__ void k_final(const float* __restrict__ pts, const float* __restrict__ wl,
                        float* __restrict__ out){
    int t = blockIdx.x * blockDim.x + threadIdx.x;
    if (t >= 512) return;
    int b = t >> 6, m = t & 63;
    const float* P = pts + (size_t)b * 64 * 64;
    float acc = 0.f;
    for (int d = 0; d < 64; ++d) acc += wl[d] * leaky(P[d * 64 + m]);
    out[t] = acc;
}

extern "C" void kernel_launch(void* const* d_in, const int* in_sizes, int n_in,
                              void* d_out, int out_size, void* d_ws, size_t ws_size,
                              hipStream_t stream){
    const float* xyz_in  = (const float*)d_in[0];
    const float* w0      = (const float*)d_in[1];
    const float* fn_wc   = (const float*)d_in[2];
    const float* fn_wg   = (const float*)d_in[3];
    const float* res_wc  = (const float*)d_in[4];
    const float* res_wg  = (const float*)d_in[5];
    const float* w_last  = (const float*)d_in[6];
    float* out = (float*)d_out;

    char* ws = (char*)d_ws;
    size_t off = 0;
    auto alloc = [&](size_t bytes) -> char* {
        char* p = ws + off;
        off = (off + bytes + 255) & ~(size_t)255;
        return p;
    };
    float* wT_fnc = (float*)alloc(2UL  * 4096 * 4);
    float* wT_fng = (float*)alloc(2UL  * 4096 * 4);
    float* wT_rc  = (float*)alloc(12UL * 4096 * 4);
    float* wT_rg  = (float*)alloc(12UL * 4096 * 4);
    float* pts_a  = (float*)alloc(8UL * 64 * 4096 * 4);
    float* pts_b  = (float*)alloc(8UL * 64 * 4096 * 4);
    float* s_buf  = (float*)alloc(8UL * 64 * 4096 * 4);
    int*   idx_b  = (int*)  alloc(8UL * 4096 * 8 * 4);
    float* xyz1   = (float*)alloc(8UL * 3 * 1024 * 4);
    float* xyz2   = (float*)alloc(8UL * 3 * 1024 * 4);
    int*   sidx   = (int*)  alloc(8UL * 1024 * 4);

    // transpose all weight matrices to [d][o]
    k_transpose<<<2,  256, 0, stream>>>(fn_wc,  wT_fnc);
    k_transpose<<<2,  256, 0, stream>>>(fn_wg,  wT_fng);
    k_transpose<<<12, 256, 0, stream>>>(res_wc, wT_rc);
    k_transpose<<<12, 256, 0, stream>>>(res_wg, wT_rg);

    int n = 4096;
    k_conv0<<<(8 * 64 * n) / 256, 256, 0, stream>>>(xyz_in, w0, pts_a, n);

    const float* cxyz = xyz_in;
    {
        dim3 kb((n + BKNN - 1) / BKNN, 8);
        k_knn<<<kb, BKNN, 0, stream>>>(cxyz, cxyz, n, n, idx_b);
    }
    float* pc = pts_a;
    float* pn = pts_b;
    for (int j = 0; j < 2; ++j){
        dim3 g((n + 255) / 256, 64, 8);
        k_gather_sum<<<g, 256, 0, stream>>>(pc, idx_b, s_buf, n);
        dim3 g2((n + 255) / 256, 8);
        k_res_conv<<<g2, 256, 0, stream>>>(pc, s_buf, wT_fnc + j * 4096, wT_fng + j * 4096, pn, n);
        float* t = pc; pc = pn; pn = t;
    }

    float* xyzbufs[2] = {xyz1, xyz2};
    for (int l = 0; l < 3; ++l){
        int np = n / 4;
        if (n == 4096)      k_fps16<<<8, 256, 0, stream>>>(cxyz, n, np, sidx);
        else if (n == 1024) k_fps4<<<8, 256, 0, stream>>>(cxyz, n, np, sidx);
        else                k_fps1<<<8, 256, 0, stream>>>(cxyz, n, np, sidx);

        float* nxyz = xyzbufs[l & 1];
        int tot = 8 * 3 * np;
        k_gather_xyz<<<(tot + 255) / 256, 256, 0, stream>>>(cxyz, sidx, nxyz, n, np);

        dim3 kg((np + BKNN - 1) / BKNN, 8);
        k_knn<<<kg, BKNN, 0, stream>>>(nxyz, cxyz, np, n, idx_b);

        dim3 pm((np + 255) / 256, 64, 8);
        k_pool_max<<<pm, 256, 0, stream>>>(pc, idx_b, pn, np, n);
        float* t = pc; pc = pn; pn = t;

        cxyz = nxyz; n = np;

        dim3 ks((n + BKNN - 1) / BKNN, 8);
        k_knn<<<ks, BKNN, 0, stream>>>(cxyz, cxyz, n, n, idx_b);

        for (int i = 0; i < 4; ++i){
            dim3 g((n + 255) / 256, 64, 8);
            k_gather_sum<<<g, 256, 0, stream>>>(pc, idx_b, s_buf, n);
            dim3 g2((n + 255) / 256, 8);
            k_res_conv<<<g2, 256, 0, stream>>>(pc, s_buf, wT_rc + (l * 4 + i) * 4096,
                                               wT_rg + (l * 4 + i) * 4096, pn, n);
            t = pc; pc = pn; pn = t;
        }
    }

    k_final<<<2, 256, 0, stream>>>(pc, w_last, out);
}

// Round 5
// 3427.752 us; speedup vs baseline: 1.9178x; 1.1638x over previous
//
#include <hip/hip_runtime.h>
#include <hip/hip_bf16.h>
#include <float.h>

#define NEG_SLOPE 0.01f

__device__ __forceinline__ float leaky(float x){ return x >= 0.0f ? x : NEG_SLOPE * x; }

// ---------------- transpose a batch of 64x64 matrices: [o][d] -> [d][o] ----------------
__global__ void k_transpose(const float* __restrict__ src, float* __restrict__ dst){
    int m = blockIdx.x;
    const float* s = src + (size_t)m * 4096;
    float* d = dst + (size_t)m * 4096;
    for (int t = threadIdx.x; t < 4096; t += blockDim.x){
        int o = t >> 6, dd = t & 63;
        d[dd * 64 + o] = s[t];
    }
}

// ---------------- first conv: 3 -> 64 ----------------
__global__ void k_conv0(const float* __restrict__ xyz, const float* __restrict__ w0,
                        float* __restrict__ out, int n){
    int t = blockIdx.x * blockDim.x + threadIdx.x;
    int nn = t % n;
    int rest = t / n;
    int o = rest & 63;
    int b = rest >> 6;
    const float* X = xyz + (size_t)b * 3 * n;
    float x = X[nn], y = X[n + nn], z = X[2 * n + nn];
    out[((size_t)b * 64 + o) * n + nn] = w0[o*3] * x + w0[o*3+1] * y + w0[o*3+2] * z;
}

// ---------------- kNN: for each query, indices of 8 nearest refs ----------------
// Top-8 kept in NAMED registers; branchless compare-swap insertion chain.
#define KNN_CHUNK 1024
#define BKNN 64

#define KNN_INS(bdX, biX) { bool c = cd < bdX; float tf = bdX; int ti = biX; \
    bdX = c ? cd : bdX; biX = c ? ci : biX; cd = c ? tf : cd; ci = c ? ti : ci; }

__global__ void __launch_bounds__(BKNN, 1)
k_knn(const float* __restrict__ q, const float* __restrict__ ref,
      int M, int Nr, int* __restrict__ idx_out){
    __shared__ float4 sref[KNN_CHUNK];
    int b = blockIdx.y;
    int m = blockIdx.x * BKNN + threadIdx.x;
    const float* Q = q + (size_t)b * 3 * M;
    const float* R = ref + (size_t)b * 3 * Nr;
    bool valid = (m < M);
    float qx = 0.f, qy = 0.f, qz = 0.f, qq = 0.f;
    if (valid){
        qx = Q[m]; qy = Q[M + m]; qz = Q[2 * M + m];
        qq = qx*qx + qy*qy + qz*qz;
    }
    float bd0 = FLT_MAX, bd1 = FLT_MAX, bd2 = FLT_MAX, bd3 = FLT_MAX;
    float bd4 = FLT_MAX, bd5 = FLT_MAX, bd6 = FLT_MAX, bd7 = FLT_MAX;
    int bi0 = 0, bi1 = 0, bi2 = 0, bi3 = 0, bi4 = 0, bi5 = 0, bi6 = 0, bi7 = 0;

    for (int base = 0; base < Nr; base += KNN_CHUNK){
        int jmax = min(KNN_CHUNK, Nr - base);
        for (int j = threadIdx.x; j < jmax; j += BKNN){
            float rx = R[base + j], ry = R[Nr + base + j], rz = R[2 * Nr + base + j];
            sref[j] = make_float4(rx, ry, rz, rx*rx + ry*ry + rz*rz);
        }
        __syncthreads();
        for (int j = 0; j < jmax; ++j){
            float4 r = sref[j];
            float dot = qx * r.x + qy * r.y + qz * r.z;
            float d = qq + r.w - 2.0f * dot;
            if (d < bd7){
                // ascending-index scan + strict '<' => lowest index wins ties (matches lax.top_k)
                float cd = d; int ci = base + j;
                KNN_INS(bd0, bi0); KNN_INS(bd1, bi1); KNN_INS(bd2, bi2); KNN_INS(bd3, bi3);
                KNN_INS(bd4, bi4); KNN_INS(bd5, bi5); KNN_INS(bd6, bi6); KNN_INS(bd7, bi7);
            }
        }
        __syncthreads();
    }
    if (valid){
        int* o = idx_out + ((size_t)b * M + m) * 8;
        o[0] = bi0; o[1] = bi1; o[2] = bi2; o[3] = bi3;
        o[4] = bi4; o[5] = bi5; o[6] = bi6; o[7] = bi7;
    }
}

// ---------------- farthest point sampling (one block of 256 per batch) ----------------
// Diagnosis history: r1 scratch spill (array state), r2 launch_bounds no-op,
// r3 found coord loads REMATERIALIZED per-iteration (VGPR=56, 48 global
// reloads/thread/iter, latency-bound at 1 wave/SIMD). Fix here: opaque asm
// pin forces coords register-resident; winner coords fetched from LDS xyz
// mirror by index (broadcast ds_read) instead of riding the shuffle tree.
// NOTE: N/NPOINT are declared as constexpr identifiers inside the body so
// nested macros (textual expansion) bind to them.
#define FPS_DECL(i) float px##i, py##i, pz##i, ds##i;
#define FPS_LOAD(i) { int gi = tid + (i) * 256; px##i = X[gi]; py##i = X[N + gi]; \
                      pz##i = X[2 * N + gi]; ds##i = 1e10f; }
#define FPS_PIN(i) asm volatile("" : "+v"(px##i), "+v"(py##i), "+v"(pz##i));
#define FPS_UPD(i) { float dx = px##i - lx, dy = py##i - ly, dz = pz##i - lz; \
    float d = dx*dx + dy*dy + dz*dz; \
    float nd = fminf(ds##i, d); ds##i = nd; \
    bool c = (nd > best); /* ascending gi scan; '>' keeps lowest gi on ties */ \
    best = c ? nd : best; bidx = c ? (tid + (i) * 256) : bidx; }

#define RPT16(M) M(0) M(1) M(2) M(3) M(4) M(5) M(6) M(7) \
                 M(8) M(9) M(10) M(11) M(12) M(13) M(14) M(15)
#define RPT4(M) M(0) M(1) M(2) M(3)
#define RPT1(M) M(0)

#define FPS_BODY(RPT, N_P, NP_P) \
    constexpr int N = N_P; \
    constexpr int NPOINT = NP_P; \
    const int b = blockIdx.x; \
    const float* X = xyz + (size_t)b * 3 * N; \
    int tid = threadIdx.x; \
    RPT(FPS_DECL) \
    RPT(FPS_LOAD) \
    RPT(FPS_PIN) \
    __shared__ float4 sxyz[N]; \
    __shared__ float2 sred[2][4]; \
    for (int t = tid; t < N; t += 256) \
        sxyz[t] = make_float4(X[t], X[N + t], X[2 * N + t], 0.f); \
    if (tid == 0) sidx[(size_t)b * NPOINT] = 0; \
    float lx = X[0], ly = X[N], lz = X[2 * N]; \
    __syncthreads(); \
    for (int i = 1; i < NPOINT; ++i){ \
        float best = -1.0f; int bidx = 0; \
        RPT(FPS_UPD) \
        _Pragma("unroll") \
        for (int off = 32; off; off >>= 1){ \
            float od = __shfl_xor(best, off); \
            int   oi = __shfl_xor(bidx, off); \
            bool c = (od > best) || (od == best && oi < bidx); \
            best = c ? od : best; bidx = c ? oi : bidx; \
        } \
        int buf = i & 1; \
        if ((tid & 63) == 0) \
            sred[buf][tid >> 6] = make_float2(best, __int_as_float(bidx)); \
        __syncthreads(); \
        float bv = sred[buf][0].x; int i0 = __float_as_int(sred[buf][0].y); \
        _Pragma("unroll") \
        for (int w = 1; w < 4; ++w){ \
            float2 tw = sred[buf][w]; int iw = __float_as_int(tw.y); \
            bool c = (tw.x > bv) || (tw.x == bv && iw < i0); \
            bv = c ? tw.x : bv; i0 = c ? iw : i0; \
        } \
        float4 wn = sxyz[i0]; \
        lx = wn.x; ly = wn.y; lz = wn.z; \
        if (tid == 0) sidx[(size_t)b * NPOINT + i] = i0; \
    }

__global__ void __launch_bounds__(256, 1)
k_fps16(const float* __restrict__ xyz, int* __restrict__ sidx){
    FPS_BODY(RPT16, 4096, 1024)
}
__global__ void __launch_bounds__(256, 1)
k_fps4(const float* __restrict__ xyz, int* __restrict__ sidx){
    FPS_BODY(RPT4, 1024, 256)
}
__global__ void __launch_bounds__(256, 1)
k_fps1(const float* __restrict__ xyz, int* __restrict__ sidx){
    FPS_BODY(RPT1, 256, 64)
}

// ---------------- gather sampled xyz ----------------
__global__ void k_gather_xyz(const float* __restrict__ xyz, const int* __restrict__ sidx,
                             float* __restrict__ out, int n, int np){
    int t = blockIdx.x * blockDim.x + threadIdx.x;
    if (t >= 8 * 3 * np) return;
    int m = t % np;
    int c = (t / np) % 3;
    int b = t / (3 * np);
    out[((size_t)b * 3 + c) * np + m] = xyz[((size_t)b * 3 + c) * n + sidx[(size_t)b * np + m]];
}

// ---------------- max-pool over k grouped neighbors ----------------
__global__ void k_pool_max(const float* __restrict__ src, const int* __restrict__ idx,
                           float* __restrict__ out, int np, int nsrc){
    int m = blockIdx.x * blockDim.x + threadIdx.x;
    if (m >= np) return;
    int d = blockIdx.y, b = blockIdx.z;
    const float* row = src + ((size_t)b * 64 + d) * nsrc;
    const int* id = idx + ((size_t)b * np + m) * 8;
    float v = -FLT_MAX;
    #pragma unroll
    for (int k = 0; k < 8; ++k) v = fmaxf(v, row[id[k]]);
    out[((size_t)b * 64 + d) * np + m] = v;
}

// ---------------- neighbor sum of leaky(points) ----------------
__global__ void k_gather_sum(const float* __restrict__ src, const int* __restrict__ idx,
                             float* __restrict__ out, int n){
    int m = blockIdx.x * blockDim.x + threadIdx.x;
    if (m >= n) return;
    int d = blockIdx.y, b = blockIdx.z;
    const float* row = src + ((size_t)b * 64 + d) * n;
    const int* id = idx + ((size_t)b * n + m) * 8;
    float v = 0.f;
    #pragma unroll
    for (int k = 0; k < 8; ++k) v += leaky(row[id[k]]);
    out[((size_t)b * 64 + d) * n + m] = v;
}

// ---------------- dual GEMM + epilogue: out = (wc@leaky(P) + wg@S)/9 + P ----------------
__global__ void __launch_bounds__(256, 1)
k_res_conv(const float* __restrict__ pts, const float* __restrict__ s,
           const float* __restrict__ wcT, const float* __restrict__ wgT,
           float* __restrict__ out, int n){
    int j = blockIdx.x * blockDim.x + threadIdx.x;
    if (j >= n) return;
    int b = blockIdx.y;
    const float* P = pts + (size_t)b * 64 * n;
    const float* S = s + (size_t)b * 64 * n;
    float acc[64];
    #pragma unroll
    for (int o = 0; o < 64; ++o) acc[o] = 0.f;
    for (int d = 0; d < 64; ++d){
        float h = leaky(P[(size_t)d * n + j]);
        float sv = S[(size_t)d * n + j];
        const float* wc = wcT + d * 64;  // uniform addresses -> s_load
        const float* wg = wgT + d * 64;
        #pragma unroll
        for (int o = 0; o < 64; ++o) acc[o] = fmaf(wc[o], h, fmaf(wg[o], sv, acc[o]));
    }
    const float inv = 1.0f / 9.0f;
    #pragma unroll
    for (int o = 0; o < 64; ++o)
        out[((size_t)b * 64 + o) * n + j] = acc[o] * inv + P[(size_t)o * n + j];
}

// ---------------- last layer: leaky -> 1x1 conv to 1 channel ----------------
__global__ void k_final(const float* __restrict__ pts, const float* __restrict__ wl,
                        float* __restrict__ out){
    int t = blockIdx.x * blockDim.x + threadIdx.x;
    if (t >= 512) return;
    int b = t >> 6, m = t & 63;
    const float* P = pts + (size_t)b * 64 * 64;
    float acc = 0.f;
    for (int d = 0; d < 64; ++d) acc += wl[d] * leaky(P[d * 64 + m]);
    out[t] = acc;
}

extern "C" void kernel_launch(void* const* d_in, const int* in_sizes, int n_in,
                              void* d_out, int out_size, void* d_ws, size_t ws_size,
                              hipStream_t stream){
    const float* xyz_in  = (const float*)d_in[0];
    const float* w0      = (const float*)d_in[1];
    const float* fn_wc   = (const float*)d_in[2];
    const float* fn_wg   = (const float*)d_in[3];
    const float* res_wc  = (const float*)d_in[4];
    const float* res_wg  = (const float*)d_in[5];
    const float* w_last  = (const float*)d_in[6];
    float* out = (float*)d_out;

    char* ws = (char*)d_ws;
    size_t off = 0;
    auto alloc = [&](size_t bytes) -> char* {
        char* p = ws + off;
        off = (off + bytes + 255) & ~(size_t)255;
        return p;
    };
    float* wT_fnc = (float*)alloc(2UL  * 4096 * 4);
    float* wT_fng = (float*)alloc(2UL  * 4096 * 4);
    float* wT_rc  = (float*)alloc(12UL * 4096 * 4);
    float* wT_rg  = (float*)alloc(12UL * 4096 * 4);
    float* pts_a  = (float*)alloc(8UL * 64 * 4096 * 4);
    float* pts_b  = (float*)alloc(8UL * 64 * 4096 * 4);
    float* s_buf  = (float*)alloc(8UL * 64 * 4096 * 4);
    int*   idx_b  = (int*)  alloc(8UL * 4096 * 8 * 4);
    float* xyz1   = (float*)alloc(8UL * 3 * 1024 * 4);
    float* xyz2   = (float*)alloc(8UL * 3 * 1024 * 4);
    int*   sidx   = (int*)  alloc(8UL * 1024 * 4);

    // transpose all weight matrices to [d][o]
    k_transpose<<<2,  256, 0, stream>>>(fn_wc,  wT_fnc);
    k_transpose<<<2,  256, 0, stream>>>(fn_wg,  wT_fng);
    k_transpose<<<12, 256, 0, stream>>>(res_wc, wT_rc);
    k_transpose<<<12, 256, 0, stream>>>(res_wg, wT_rg);

    int n = 4096;
    k_conv0<<<(8 * 64 * n) / 256, 256, 0, stream>>>(xyz_in, w0, pts_a, n);

    const float* cxyz = xyz_in;
    {
        dim3 kb((n + BKNN - 1) / BKNN, 8);
        k_knn<<<kb, BKNN, 0, stream>>>(cxyz, cxyz, n, n, idx_b);
    }
    float* pc = pts_a;
    float* pn = pts_b;
    for (int j = 0; j < 2; ++j){
        dim3 g((n + 255) / 256, 64, 8);
        k_gather_sum<<<g, 256, 0, stream>>>(pc, idx_b, s_buf, n);
        dim3 g2((n + 255) / 256, 8);
        k_res_conv<<<g2, 256, 0, stream>>>(pc, s_buf, wT_fnc + j * 4096, wT_fng + j * 4096, pn, n);
        float* t = pc; pc = pn; pn = t;
    }

    float* xyzbufs[2] = {xyz1, xyz2};
    for (int l = 0; l < 3; ++l){
        int np = n / 4;
        if (n == 4096)      k_fps16<<<8, 256, 0, stream>>>(cxyz, sidx);
        else if (n == 1024) k_fps4<<<8, 256, 0, stream>>>(cxyz, sidx);
        else                k_fps1<<<8, 256, 0, stream>>>(cxyz, sidx);

        float* nxyz = xyzbufs[l & 1];
        int tot = 8 * 3 * np;
        k_gather_xyz<<<(tot + 255) / 256, 256, 0, stream>>>(cxyz, sidx, nxyz, n, np);

        dim3 kg((np + BKNN - 1) / BKNN, 8);
        k_knn<<<kg, BKNN, 0, stream>>>(nxyz, cxyz, np, n, idx_b);

        dim3 pm((np + 255) / 256, 64, 8);
        k_pool_max<<<pm, 256, 0, stream>>>(pc, idx_b, pn, np, n);
        float* t = pc; pc = pn; pn = t;

        cxyz = nxyz; n = np;

        dim3 ks((n + BKNN - 1) / BKNN, 8);
        k_knn<<<ks, BKNN, 0, stream>>>(cxyz, cxyz, n, n, idx_b);

        for (int i = 0; i < 4; ++i){
            dim3 g((n + 255) / 256, 64, 8);
            k_gather_sum<<<g, 256, 0, stream>>>(pc, idx_b, s_buf, n);
            dim3 g2((n + 255) / 256, 8);
            k_res_conv<<<g2, 256, 0, stream>>>(pc, s_buf, wT_rc + (l * 4 + i) * 4096,
                                               wT_rg + (l * 4 + i) * 4096, pn, n);
            t = pc; pc = pn; pn = t;
        }
    }

    k_final<<<2, 256, 0, stream>>>(pc, w_last, out);
}

// Round 6
// 3162.956 us; speedup vs baseline: 2.0783x; 1.0837x over previous
//
#include <hip/hip_runtime.h>
#include <hip/hip_bf16.h>
#include <float.h>

#define NEG_SLOPE 0.01f

__device__ __forceinline__ float leaky(float x){ return x >= 0.0f ? x : NEG_SLOPE * x; }

// ---------------- transpose a batch of 64x64 matrices: [o][d] -> [d][o] ----------------
__global__ void k_transpose(const float* __restrict__ src, float* __restrict__ dst){
    int m = blockIdx.x;
    const float* s = src + (size_t)m * 4096;
    float* d = dst + (size_t)m * 4096;
    for (int t = threadIdx.x; t < 4096; t += blockDim.x){
        int o = t >> 6, dd = t & 63;
        d[dd * 64 + o] = s[t];
    }
}

// ---------------- first conv: 3 -> 64 ----------------
__global__ void k_conv0(const float* __restrict__ xyz, const float* __restrict__ w0,
                        float* __restrict__ out, int n){
    int t = blockIdx.x * blockDim.x + threadIdx.x;
    int nn = t % n;
    int rest = t / n;
    int o = rest & 63;
    int b = rest >> 6;
    const float* X = xyz + (size_t)b * 3 * n;
    float x = X[nn], y = X[n + nn], z = X[2 * n + nn];
    out[((size_t)b * 64 + o) * n + nn] = w0[o*3] * x + w0[o*3+1] * y + w0[o*3+2] * z;
}

// ---------------- kNN: for each query, indices of 8 nearest refs ----------------
// Top-8 kept in NAMED registers; branchless compare-swap insertion chain.
#define KNN_CHUNK 1024
#define BKNN 64

#define KNN_INS(bdX, biX) { bool c = cd < bdX; float tf = bdX; int ti = biX; \
    bdX = c ? cd : bdX; biX = c ? ci : biX; cd = c ? tf : cd; ci = c ? ti : ti = ti; biX = biX; }
#undef KNN_INS
#define KNN_INS(bdX, biX) { bool c = cd < bdX; float tf = bdX; int ti = biX; \
    bdX = c ? cd : bdX; biX = c ? ci : biX; cd = c ? tf : cd; ci = c ? ti : ci; }

__global__ void __launch_bounds__(BKNN, 1)
k_knn(const float* __restrict__ q, const float* __restrict__ ref,
      int M, int Nr, int* __restrict__ idx_out){
    __shared__ float4 sref[KNN_CHUNK];
    int b = blockIdx.y;
    int m = blockIdx.x * BKNN + threadIdx.x;
    const float* Q = q + (size_t)b * 3 * M;
    const float* R = ref + (size_t)b * 3 * Nr;
    bool valid = (m < M);
    float qx = 0.f, qy = 0.f, qz = 0.f, qq = 0.f;
    if (valid){
        qx = Q[m]; qy = Q[M + m]; qz = Q[2 * M + m];
        qq = qx*qx + qy*qy + qz*qz;
    }
    float bd0 = FLT_MAX, bd1 = FLT_MAX, bd2 = FLT_MAX, bd3 = FLT_MAX;
    float bd4 = FLT_MAX, bd5 = FLT_MAX, bd6 = FLT_MAX, bd7 = FLT_MAX;
    int bi0 = 0, bi1 = 0, bi2 = 0, bi3 = 0, bi4 = 0, bi5 = 0, bi6 = 0, bi7 = 0;

    for (int base = 0; base < Nr; base += KNN_CHUNK){
        int jmax = min(KNN_CHUNK, Nr - base);
        for (int j = threadIdx.x; j < jmax; j += BKNN){
            float rx = R[base + j], ry = R[Nr + base + j], rz = R[2 * Nr + base + j];
            sref[j] = make_float4(rx, ry, rz, rx*rx + ry*ry + rz*rz);
        }
        __syncthreads();
        for (int j = 0; j < jmax; ++j){
            float4 r = sref[j];
            float dot = qx * r.x + qy * r.y + qz * r.z;
            float d = qq + r.w - 2.0f * dot;
            if (d < bd7){
                // ascending-index scan + strict '<' => lowest index wins ties (matches lax.top_k)
                float cd = d; int ci = base + j;
                KNN_INS(bd0, bi0); KNN_INS(bd1, bi1); KNN_INS(bd2, bi2); KNN_INS(bd3, bi3);
                KNN_INS(bd4, bi4); KNN_INS(bd5, bi5); KNN_INS(bd6, bi6); KNN_INS(bd7, bi7);
            }
        }
        __syncthreads();
    }
    if (valid){
        int* o = idx_out + ((size_t)b * M + m) * 8;
        o[0] = bi0; o[1] = bi1; o[2] = bi2; o[3] = bi3;
        o[4] = bi4; o[5] = bi5; o[6] = bi6; o[7] = bi7;
    }
}

// ---------------- farthest point sampling ----------------
// r5 diagnosis: 2230 cyc/iter was cross-lane latency (__shfl = ds_bpermute,
// ~120cyc x 6 serial levels, + dependent sxyz ds_read). Fix: DPP reduction
// (row_shr 1/2/4/8 + row_bcast15/31) on the VALU, candidate packed as
// (float_bits(dist)<<32)|~idx for exact single-cmp tie-breaks, winner coords
// carried through the DPP selects (kills the LDS xyz mirror entirely).
// fps4/fps1 run as ONE wave: no barriers, v_readlane broadcast.

template<int CTRL>
__device__ __forceinline__ void dpp_step(unsigned long long &bp, float &x, float &y, float &z){
    unsigned h = (unsigned)(bp >> 32), l = (unsigned)bp;
    unsigned th = (unsigned)__builtin_amdgcn_update_dpp(0, (int)h, CTRL, 0xF, 0xF, true);
    unsigned tl = (unsigned)__builtin_amdgcn_update_dpp(0, (int)l, CTRL, 0xF, 0xF, true);
    float tx = __int_as_float(__builtin_amdgcn_update_dpp(0, __float_as_int(x), CTRL, 0xF, 0xF, true));
    float ty = __int_as_float(__builtin_amdgcn_update_dpp(0, __float_as_int(y), CTRL, 0xF, 0xF, true));
    float tz = __int_as_float(__builtin_amdgcn_update_dpp(0, __float_as_int(z), CTRL, 0xF, 0xF, true));
    unsigned long long tp = ((unsigned long long)th << 32) | tl;
    bool c = tp > bp;
    bp = c ? tp : bp; x = c ? tx : x; y = c ? ty : y; z = c ? tz : z;
}
// after these 6 steps lane 63 holds the wave's max (with coords)
#define DPP_REDUCE(bp, bx, by, bz) \
    dpp_step<0x111>(bp, bx, by, bz); \
    dpp_step<0x112>(bp, bx, by, bz); \
    dpp_step<0x114>(bp, bx, by, bz); \
    dpp_step<0x118>(bp, bx, by, bz); \
    dpp_step<0x142>(bp, bx, by, bz); \
    dpp_step<0x143>(bp, bx, by, bz);

#define FPS_DECL(i) float px##i, py##i, pz##i, ds##i; unsigned nti##i;
#define FPS_LOAD(i) { int gi = tid + (i) * T; px##i = X[gi]; py##i = X[N + gi]; \
                      pz##i = X[2 * N + gi]; ds##i = 1e10f; nti##i = ~(unsigned)gi; }
#define FPS_PIN(i) asm volatile("" : "+v"(px##i), "+v"(py##i), "+v"(pz##i));
// dist >= 0 always => float bit pattern order == float order; ~gi larger => gi smaller,
// so u64 max reproduces (dist >, tie: idx <) exactly.
#define FPS_UPD(i) { float dx = px##i - lx, dy = py##i - ly, dz = pz##i - lz; \
    float d = dx*dx + dy*dy + dz*dz; \
    float nd = fminf(ds##i, d); ds##i = nd; \
    unsigned long long cp = ((unsigned long long)__float_as_uint(nd) << 32) | nti##i; \
    bool c = cp > bp; \
    bp = c ? cp : bp; bx = c ? px##i : bx; by = c ? py##i : by; bz = c ? pz##i : bz; }

#define RPT16(M) M(0) M(1) M(2) M(3) M(4) M(5) M(6) M(7) \
                 M(8) M(9) M(10) M(11) M(12) M(13) M(14) M(15)
#define RPT4(M) M(0) M(1) M(2) M(3)

// multi-wave (256 threads, 4 waves): one barrier/iter, coords carried via LDS
#define FPS_BODY_MW(RPT, N_P, NP_P) \
    constexpr int N = N_P, NPOINT = NP_P, T = 256; \
    const int b = blockIdx.x; \
    const float* X = xyz + (size_t)b * 3 * N; \
    int tid = threadIdx.x; \
    RPT(FPS_DECL) RPT(FPS_LOAD) RPT(FPS_PIN) \
    __shared__ float4 sA[2][4]; \
    __shared__ unsigned sB[2][4]; \
    if (tid == 0) sidx[(size_t)b * NPOINT] = 0; \
    float lx = X[0], ly = X[N], lz = X[2 * N]; \
    for (int i = 1; i < NPOINT; ++i){ \
        unsigned long long bp = 0; float bx = 0.f, by = 0.f, bz = 0.f; \
        RPT(FPS_UPD) \
        DPP_REDUCE(bp, bx, by, bz) \
        int buf = i & 1; \
        if ((tid & 63) == 63){ \
            sA[buf][tid >> 6] = make_float4(bx, by, bz, __uint_as_float((unsigned)(bp >> 32))); \
            sB[buf][tid >> 6] = (unsigned)bp; \
        } \
        __syncthreads(); \
        float4 w0 = sA[buf][0]; \
        unsigned long long pp = ((unsigned long long)__float_as_uint(w0.w) << 32) | sB[buf][0]; \
        lx = w0.x; ly = w0.y; lz = w0.z; \
        _Pragma("unroll") \
        for (int k = 1; k < 4; ++k){ \
            float4 wk = sA[buf][k]; \
            unsigned long long pk = ((unsigned long long)__float_as_uint(wk.w) << 32) | sB[buf][k]; \
            bool c = pk > pp; \
            pp = c ? pk : pp; lx = c ? wk.x : lx; ly = c ? wk.y : ly; lz = c ? wk.z : lz; \
        } \
        if (tid == 0) sidx[(size_t)b * NPOINT + i] = (int)~(unsigned)pp; \
    }

// single-wave (64 threads): no barrier, readlane broadcast from lane 63
#define FPS_BODY_SW(RPT, N_P, NP_P) \
    constexpr int N = N_P, NPOINT = NP_P, T = 64; \
    const int b = blockIdx.x; \
    const float* X = xyz + (size_t)b * 3 * N; \
    int tid = threadIdx.x; \
    RPT(FPS_DECL) RPT(FPS_LOAD) RPT(FPS_PIN) \
    if (tid == 0) sidx[(size_t)b * NPOINT] = 0; \
    float lx = X[0], ly = X[N], lz = X[2 * N]; \
    for (int i = 1; i < NPOINT; ++i){ \
        unsigned long long bp = 0; float bx = 0.f, by = 0.f, bz = 0.f; \
        RPT(FPS_UPD) \
        DPP_REDUCE(bp, bx, by, bz) \
        lx = __int_as_float(__builtin_amdgcn_readlane(__float_as_int(bx), 63)); \
        ly = __int_as_float(__builtin_amdgcn_readlane(__float_as_int(by), 63)); \
        lz = __int_as_float(__builtin_amdgcn_readlane(__float_as_int(bz), 63)); \
        unsigned wl = (unsigned)__builtin_amdgcn_readlane((int)(unsigned)bp, 63); \
        if (tid == 0) sidx[(size_t)b * NPOINT + i] = (int)~wl; \
    }

__global__ void __launch_bounds__(256, 1)
k_fps16(const float* __restrict__ xyz, int* __restrict__ sidx){
    FPS_BODY_MW(RPT16, 4096, 1024)
}
__global__ void __launch_bounds__(64, 1)
k_fps4(const float* __restrict__ xyz, int* __restrict__ sidx){
    FPS_BODY_SW(RPT16, 1024, 256)
}
__global__ void __launch_bounds__(64, 1)
k_fps1(const float* __restrict__ xyz, int* __restrict__ sidx){
    FPS_BODY_SW(RPT4, 256, 64)
}

// ---------------- gather sampled xyz ----------------
__global__ void k_gather_xyz(const float* __restrict__ xyz, const int* __restrict__ sidx,
                             float* __restrict__ out, int n, int np){
    int t = blockIdx.x * blockDim.x + threadIdx.x;
    if (t >= 8 * 3 * np) return;
    int m = t % np;
    int c = (t / np) % 3;
    int b = t / (3 * np);
    out[((size_t)b * 3 + c) * np + m] = xyz[((size_t)b * 3 + c) * n + sidx[(size_t)b * np + m]];
}

// ---------------- max-pool over k grouped neighbors ----------------
__global__ void k_pool_max(const float* __restrict__ src, const int* __restrict__ idx,
                           float* __restrict__ out, int np, int nsrc){
    int m = blockIdx.x * blockDim.x + threadIdx.x;
    if (m >= np) return;
    int d = blockIdx.y, b = blockIdx.z;
    const float* row = src + ((size_t)b * 64 + d) * nsrc;
    const int* id = idx + ((size_t)b * np + m) * 8;
    float v = -FLT_MAX;
    #pragma unroll
    for (int k = 0; k < 8; ++k) v = fmaxf(v, row[id[k]]);
    out[((size_t)b * 64 + d) * np + m] = v;
}

// ---------------- neighbor sum of leaky(points) ----------------
__global__ void k_gather_sum(const float* __restrict__ src, const int* __restrict__ idx,
                             float* __restrict__ out, int n){
    int m = blockIdx.x * blockDim.x + threadIdx.x;
    if (m >= n) return;
    int d = blockIdx.y, b = blockIdx.z;
    const float* row = src + ((size_t)b * 64 + d) * n;
    const int* id = idx + ((size_t)b * n + m) * 8;
    float v = 0.f;
    #pragma unroll
    for (int k = 0; k < 8; ++k) v += leaky(row[id[k]]);
    out[((size_t)b * 64 + d) * n + m] = v;
}

// ---------------- dual GEMM + epilogue: out = (wc@leaky(P) + wg@S)/9 + P ----------------
__global__ void __launch_bounds__(256, 1)
k_res_conv(const float* __restrict__ pts, const float* __restrict__ s,
           const float* __restrict__ wcT, const float* __restrict__ wgT,
           float* __restrict__ out, int n){
    int j = blockIdx.x * blockDim.x + threadIdx.x;
    if (j >= n) return;
    int b = blockIdx.y;
    const float* P = pts + (size_t)b * 64 * n;
    const float* S = s + (size_t)b * 64 * n;
    float acc[64];
    #pragma unroll
    for (int o = 0; o < 64; ++o) acc[o] = 0.f;
    for (int d = 0; d < 64; ++d){
        float h = leaky(P[(size_t)d * n + j]);
        float sv = S[(size_t)d * n + j];
        const float* wc = wcT + d * 64;  // uniform addresses -> s_load
        const float* wg = wgT + d * 64;
        #pragma unroll
        for (int o = 0; o < 64; ++o) acc[o] = fmaf(wc[o], h, fmaf(wg[o], sv, acc[o]));
    }
    const float inv = 1.0f / 9.0f;
    #pragma unroll
    for (int o = 0; o < 64; ++o)
        out[((size_t)b * 64 + o) * n + j] = acc[o] * inv + P[(size_t)o * n + j];
}

// ---------------- last layer: leaky -> 1x1 conv to 1 channel ----------------
__global__ void k_final(const float* __restrict__ pts, const float* __restrict__ wl,
                        float* __restrict__ out){
    int t = blockIdx.x * blockDim.x + threadIdx.x;
    if (t >= 512) return;
    int b = t >> 6, m = t & 63;
    const float* P = pts + (size_t)b * 64 * 64;
    float acc = 0.f;
    for (int d = 0; d < 64; ++d) acc += wl[d] * leaky(P[d * 64 + m]);
    out[t] = acc;
}

extern "C" void kernel_launch(void* const* d_in, const int* in_sizes, int n_in,
                              void* d_out, int out_size, void* d_ws, size_t ws_size,
                              hipStream_t stream){
    const float* xyz_in  = (const float*)d_in[0];
    const float* w0      = (const float*)d_in[1];
    const float* fn_wc   = (const float*)d_in[2];
    const float* fn_wg   = (const float*)d_in[3];
    const float* res_wc  = (const float*)d_in[4];
    const float* res_wg  = (const float*)d_in[5];
    const float* w_last  = (const float*)d_in[6];
    float* out = (float*)d_out;

    char* ws = (char*)d_ws;
    size_t off = 0;
    auto alloc = [&](size_t bytes) -> char* {
        char* p = ws + off;
        off = (off + bytes + 255) & ~(size_t)255;
        return p;
    };
    float* wT_fnc = (float*)alloc(2UL  * 4096 * 4);
    float* wT_fng = (float*)alloc(2UL  * 4096 * 4);
    float* wT_rc  = (float*)alloc(12UL * 4096 * 4);
    float* wT_rg  = (float*)alloc(12UL * 4096 * 4);
    float* pts_a  = (float*)alloc(8UL * 64 * 4096 * 4);
    float* pts_b  = (float*)alloc(8UL * 64 * 4096 * 4);
    float* s_buf  = (float*)alloc(8UL * 64 * 4096 * 4);
    int*   idx_b  = (int*)  alloc(8UL * 4096 * 8 * 4);
    float* xyz1   = (float*)alloc(8UL * 3 * 1024 * 4);
    float* xyz2   = (float*)alloc(8UL * 3 * 1024 * 4);
    int*   sidx   = (int*)  alloc(8UL * 1024 * 4);

    // transpose all weight matrices to [d][o]
    k_transpose<<<2,  256, 0, stream>>>(fn_wc,  wT_fnc);
    k_transpose<<<2,  256, 0, stream>>>(fn_wg,  wT_fng);
    k_transpose<<<12, 256, 0, stream>>>(res_wc, wT_rc);
    k_transpose<<<12, 256, 0, stream>>>(res_wg, wT_rg);

    int n = 4096;
    k_conv0<<<(8 * 64 * n) / 256, 256, 0, stream>>>(xyz_in, w0, pts_a, n);

    const float* cxyz = xyz_in;
    {
        dim3 kb((n + BKNN - 1) / BKNN, 8);
        k_knn<<<kb, BKNN, 0, stream>>>(cxyz, cxyz, n, n, idx_b);
    }
    float* pc = pts_a;
    float* pn = pts_b;
    for (int j = 0; j < 2; ++j){
        dim3 g((n + 255) / 256, 64, 8);
        k_gather_sum<<<g, 256, 0, stream>>>(pc, idx_b, s_buf, n);
        dim3 g2((n + 255) / 256, 8);
        k_res_conv<<<g2, 256, 0, stream>>>(pc, s_buf, wT_fnc + j * 4096, wT_fng + j * 4096, pn, n);
        float* t = pc; pc = pn; pn = t;
    }

    float* xyzbufs[2] = {xyz1, xyz2};
    for (int l = 0; l < 3; ++l){
        int np = n / 4;
        if (n == 4096)      k_fps16<<<8, 256, 0, stream>>>(cxyz, sidx);
        else if (n == 1024) k_fps4<<<8, 64, 0, stream>>>(cxyz, sidx);
        else                k_fps1<<<8, 64, 0, stream>>>(cxyz, sidx);

        float* nxyz = xyzbufs[l & 1];
        int tot = 8 * 3 * np;
        k_gather_xyz<<<(tot + 255) / 256, 256, 0, stream>>>(cxyz, sidx, nxyz, n, np);

        dim3 kg((np + BKNN - 1) / BKNN, 8);
        k_knn<<<kg, BKNN, 0, stream>>>(nxyz, cxyz, np, n, idx_b);

        dim3 pm((np + 255) / 256, 64, 8);
        k_pool_max<<<pm, 256, 0, stream>>>(pc, idx_b, pn, np, n);
        float* t = pc; pc = pn; pn = t;

        cxyz = nxyz; n = np;

        dim3 ks((n + BKNN - 1) / BKNN, 8);
        k_knn<<<ks, BKNN, 0, stream>>>(cxyz, cxyz, n, n, idx_b);

        for (int i = 0; i < 4; ++i){
            dim3 g((n + 255) / 256, 64, 8);
            k_gather_sum<<<g, 256, 0, stream>>>(pc, idx_b, s_buf, n);
            dim3 g2((n + 255) / 256, 8);
            k_res_conv<<<g2, 256, 0, stream>>>(pc, s_buf, wT_rc + (l * 4 + i) * 4096,
                                               wT_rg + (l * 4 + i) * 4096, pn, n);
            t = pc; pc = pn; pn = t;
        }
    }

    k_final<<<2, 256, 0, stream>>>(pc, w_last, out);
}

// Round 7
// 2828.867 us; speedup vs baseline: 2.3238x; 1.1181x over previous
//
#include <hip/hip_runtime.h>
#include <hip/hip_bf16.h>
#include <float.h>

#define NEG_SLOPE 0.01f

__device__ __forceinline__ float leaky(float x){ return x >= 0.0f ? x : NEG_SLOPE * x; }

// ---------------- transpose a batch of 64x64 matrices: [o][d] -> [d][o] ----------------
__global__ void k_transpose(const float* __restrict__ src, float* __restrict__ dst){
    int m = blockIdx.x;
    const float* s = src + (size_t)m * 4096;
    float* d = dst + (size_t)m * 4096;
    for (int t = threadIdx.x; t < 4096; t += blockDim.x){
        int o = t >> 6, dd = t & 63;
        d[dd * 64 + o] = s[t];
    }
}

// ---------------- first conv: 3 -> 64 ----------------
__global__ void k_conv0(const float* __restrict__ xyz, const float* __restrict__ w0,
                        float* __restrict__ out, int n){
    int t = blockIdx.x * blockDim.x + threadIdx.x;
    int nn = t % n;
    int rest = t / n;
    int o = rest & 63;
    int b = rest >> 6;
    const float* X = xyz + (size_t)b * 3 * n;
    float x = X[nn], y = X[n + nn], z = X[2 * n + nn];
    out[((size_t)b * 64 + o) * n + nn] = w0[o*3] * x + w0[o*3+1] * y + w0[o*3+2] * z;
}

// ---------------- kNN: for each query, indices of 8 nearest refs ----------------
// Top-8 kept in NAMED registers; branchless compare-swap insertion chain.
#define KNN_CHUNK 1024
#define BKNN 64

#define KNN_INS(bdX, biX) { bool c = cd < bdX; float tf = bdX; int ti = biX; \
    bdX = c ? cd : bdX; biX = c ? ci : biX; cd = c ? tf : cd; ci = c ? ti : ci; }

__global__ void __launch_bounds__(BKNN, 1)
k_knn(const float* __restrict__ q, const float* __restrict__ ref,
      int M, int Nr, int* __restrict__ idx_out){
    __shared__ float4 sref[KNN_CHUNK];
    int b = blockIdx.y;
    int m = blockIdx.x * BKNN + threadIdx.x;
    const float* Q = q + (size_t)b * 3 * M;
    const float* R = ref + (size_t)b * 3 * Nr;
    bool valid = (m < M);
    float qx = 0.f, qy = 0.f, qz = 0.f, qq = 0.f;
    if (valid){
        qx = Q[m]; qy = Q[M + m]; qz = Q[2 * M + m];
        qq = qx*qx + qy*qy + qz*qz;
    }
    float bd0 = FLT_MAX, bd1 = FLT_MAX, bd2 = FLT_MAX, bd3 = FLT_MAX;
    float bd4 = FLT_MAX, bd5 = FLT_MAX, bd6 = FLT_MAX, bd7 = FLT_MAX;
    int bi0 = 0, bi1 = 0, bi2 = 0, bi3 = 0, bi4 = 0, bi5 = 0, bi6 = 0, bi7 = 0;

    for (int base = 0; base < Nr; base += KNN_CHUNK){
        int jmax = min(KNN_CHUNK, Nr - base);
        for (int j = threadIdx.x; j < jmax; j += BKNN){
            float rx = R[base + j], ry = R[Nr + base + j], rz = R[2 * Nr + base + j];
            sref[j] = make_float4(rx, ry, rz, rx*rx + ry*ry + rz*rz);
        }
        __syncthreads();
        for (int j = 0; j < jmax; ++j){
            float4 r = sref[j];
            float dot = qx * r.x + qy * r.y + qz * r.z;
            float d = qq + r.w - 2.0f * dot;
            if (d < bd7){
                // ascending-index scan + strict '<' => lowest index wins ties (matches lax.top_k)
                float cd = d; int ci = base + j;
                KNN_INS(bd0, bi0); KNN_INS(bd1, bi1); KNN_INS(bd2, bi2); KNN_INS(bd3, bi3);
                KNN_INS(bd4, bi4); KNN_INS(bd5, bi5); KNN_INS(bd6, bi6); KNN_INS(bd7, bi7);
            }
        }
        __syncthreads();
    }
    if (valid){
        int* o = idx_out + ((size_t)b * M + m) * 8;
        o[0] = bi0; o[1] = bi1; o[2] = bi2; o[3] = bi3;
        o[4] = bi4; o[5] = bi5; o[6] = bi6; o[7] = bi7;
    }
}

// ---------------- farthest point sampling ----------------
// DPP reduction (row_shr 1/2/4/8 + row_bcast15/31) on the VALU; candidate
// packed as (float_bits(dist)<<32)|~idx for exact single-cmp tie-breaks;
// winner coords carried through the DPP selects. fps4/fps1: ONE wave,
// readlane broadcast, zero barriers.

template<int CTRL>
__device__ __forceinline__ void dpp_step(unsigned long long &bp, float &x, float &y, float &z){
    unsigned h = (unsigned)(bp >> 32), l = (unsigned)bp;
    unsigned th = (unsigned)__builtin_amdgcn_update_dpp(0, (int)h, CTRL, 0xF, 0xF, true);
    unsigned tl = (unsigned)__builtin_amdgcn_update_dpp(0, (int)l, CTRL, 0xF, 0xF, true);
    float tx = __int_as_float(__builtin_amdgcn_update_dpp(0, __float_as_int(x), CTRL, 0xF, 0xF, true));
    float ty = __int_as_float(__builtin_amdgcn_update_dpp(0, __float_as_int(y), CTRL, 0xF, 0xF, true));
    float tz = __int_as_float(__builtin_amdgcn_update_dpp(0, __float_as_int(z), CTRL, 0xF, 0xF, true));
    unsigned long long tp = ((unsigned long long)th << 32) | tl;
    bool c = tp > bp;
    bp = c ? tp : bp; x = c ? tx : x; y = c ? ty : y; z = c ? tz : z;
}
// after these 6 steps lane 63 holds the wave's max (with coords)
#define DPP_REDUCE(bp, bx, by, bz) \
    dpp_step<0x111>(bp, bx, by, bz); \
    dpp_step<0x112>(bp, bx, by, bz); \
    dpp_step<0x114>(bp, bx, by, bz); \
    dpp_step<0x118>(bp, bx, by, bz); \
    dpp_step<0x142>(bp, bx, by, bz); \
    dpp_step<0x143>(bp, bx, by, bz);

#define FPS_DECL(i) float px##i, py##i, pz##i, ds##i; unsigned nti##i;
#define FPS_LOAD(i) { int gi = tid + (i) * T; px##i = X[gi]; py##i = X[N + gi]; \
                      pz##i = X[2 * N + gi]; ds##i = 1e10f; nti##i = ~(unsigned)gi; }
#define FPS_PIN(i) asm volatile("" : "+v"(px##i), "+v"(py##i), "+v"(pz##i));
// dist >= 0 always => float bit pattern order == float order; ~gi larger => gi smaller,
// so u64 max reproduces (dist >, tie: idx <) exactly.
#define FPS_UPD(i) { float dx = px##i - lx, dy = py##i - ly, dz = pz##i - lz; \
    float d = dx*dx + dy*dy + dz*dz; \
    float nd = fminf(ds##i, d); ds##i = nd; \
    unsigned long long cp = ((unsigned long long)__float_as_uint(nd) << 32) | nti##i; \
    bool c = cp > bp; \
    bp = c ? cp : bp; bx = c ? px##i : bx; by = c ? py##i : by; bz = c ? pz##i : bz; }

#define RPT16(M) M(0) M(1) M(2) M(3) M(4) M(5) M(6) M(7) \
                 M(8) M(9) M(10) M(11) M(12) M(13) M(14) M(15)
#define RPT4(M) M(0) M(1) M(2) M(3)

// multi-wave (256 threads, 4 waves): one barrier/iter, coords carried via LDS
#define FPS_BODY_MW(RPT, N_P, NP_P) \
    constexpr int N = N_P, NPOINT = NP_P, T = 256; \
    const int b = blockIdx.x; \
    const float* X = xyz + (size_t)b * 3 * N; \
    int tid = threadIdx.x; \
    RPT(FPS_DECL) RPT(FPS_LOAD) RPT(FPS_PIN) \
    __shared__ float4 sA[2][4]; \
    __shared__ unsigned sB[2][4]; \
    if (tid == 0) sidx[(size_t)b * NPOINT] = 0; \
    float lx = X[0], ly = X[N], lz = X[2 * N]; \
    for (int i = 1; i < NPOINT; ++i){ \
        unsigned long long bp = 0; float bx = 0.f, by = 0.f, bz = 0.f; \
        RPT(FPS_UPD) \
        DPP_REDUCE(bp, bx, by, bz) \
        int buf = i & 1; \
        if ((tid & 63) == 63){ \
            sA[buf][tid >> 6] = make_float4(bx, by, bz, __uint_as_float((unsigned)(bp >> 32))); \
            sB[buf][tid >> 6] = (unsigned)bp; \
        } \
        __syncthreads(); \
        float4 w0 = sA[buf][0]; \
        unsigned long long pp = ((unsigned long long)__float_as_uint(w0.w) << 32) | sB[buf][0]; \
        lx = w0.x; ly = w0.y; lz = w0.z; \
        _Pragma("unroll") \
        for (int k = 1; k < 4; ++k){ \
            float4 wk = sA[buf][k]; \
            unsigned long long pk = ((unsigned long long)__float_as_uint(wk.w) << 32) | sB[buf][k]; \
            bool c = pk > pp; \
            pp = c ? pk : pp; lx = c ? wk.x : lx; ly = c ? wk.y : ly; lz = c ? wk.z : lz; \
        } \
        if (tid == 0) sidx[(size_t)b * NPOINT + i] = (int)~(unsigned)pp; \
    }

// single-wave (64 threads): no barrier, readlane broadcast from lane 63
#define FPS_BODY_SW(RPT, N_P, NP_P) \
    constexpr int N = N_P, NPOINT = NP_P, T = 64; \
    const int b = blockIdx.x; \
    const float* X = xyz + (size_t)b * 3 * N; \
    int tid = threadIdx.x; \
    RPT(FPS_DECL) RPT(FPS_LOAD) RPT(FPS_PIN) \
    if (tid == 0) sidx[(size_t)b * NPOINT] = 0; \
    float lx = X[0], ly = X[N], lz = X[2 * N]; \
    for (int i = 1; i < NPOINT; ++i){ \
        unsigned long long bp = 0; float bx = 0.f, by = 0.f, bz = 0.f; \
        RPT(FPS_UPD) \
        DPP_REDUCE(bp, bx, by, bz) \
        lx = __int_as_float(__builtin_amdgcn_readlane(__float_as_int(bx), 63)); \
        ly = __int_as_float(__builtin_amdgcn_readlane(__float_as_int(by), 63)); \
        lz = __int_as_float(__builtin_amdgcn_readlane(__float_as_int(bz), 63)); \
        unsigned wl = (unsigned)__builtin_amdgcn_readlane((int)(unsigned)bp, 63); \
        if (tid == 0) sidx[(size_t)b * NPOINT + i] = (int)~wl; \
    }

__global__ void __launch_bounds__(256, 1)
k_fps16(const float* __restrict__ xyz, int* __restrict__ sidx){
    FPS_BODY_MW(RPT16, 4096, 1024)
}
__global__ void __launch_bounds__(64, 1)
k_fps4(const float* __restrict__ xyz, int* __restrict__ sidx){
    FPS_BODY_SW(RPT16, 1024, 256)
}
__global__ void __launch_bounds__(64, 1)
k_fps1(const float* __restrict__ xyz, int* __restrict__ sidx){
    FPS_BODY_SW(RPT4, 256, 64)
}

// ---------------- gather sampled xyz ----------------
__global__ void k_gather_xyz(const float* __restrict__ xyz, const int* __restrict__ sidx,
                             float* __restrict__ out, int n, int np){
    int t = blockIdx.x * blockDim.x + threadIdx.x;
    if (t >= 8 * 3 * np) return;
    int m = t % np;
    int c = (t / np) % 3;
    int b = t / (3 * np);
    out[((size_t)b * 3 + c) * np + m] = xyz[((size_t)b * 3 + c) * n + sidx[(size_t)b * np + m]];
}

// ---------------- max-pool over k grouped neighbors ----------------
__global__ void k_pool_max(const float* __restrict__ src, const int* __restrict__ idx,
                           float* __restrict__ out, int np, int nsrc){
    int m = blockIdx.x * blockDim.x + threadIdx.x;
    if (m >= np) return;
    int d = blockIdx.y, b = blockIdx.z;
    const float* row = src + ((size_t)b * 64 + d) * nsrc;
    const int* id = idx + ((size_t)b * np + m) * 8;
    float v = -FLT_MAX;
    #pragma unroll
    for (int k = 0; k < 8; ++k) v = fmaxf(v, row[id[k]]);
    out[((size_t)b * 64 + d) * np + m] = v;
}

// ---------------- neighbor sum of leaky(points) ----------------
__global__ void k_gather_sum(const float* __restrict__ src, const int* __restrict__ idx,
                             float* __restrict__ out, int n){
    int m = blockIdx.x * blockDim.x + threadIdx.x;
    if (m >= n) return;
    int d = blockIdx.y, b = blockIdx.z;
    const float* row = src + ((size_t)b * 64 + d) * n;
    const int* id = idx + ((size_t)b * n + m) * 8;
    float v = 0.f;
    #pragma unroll
    for (int k = 0; k < 8; ++k) v += leaky(row[id[k]]);
    out[((size_t)b * 64 + d) * n + m] = v;
}

// ---------------- dual GEMM + epilogue: out = (wc@leaky(P) + wg@S)/9 + P ----------------
// r6 diagnosis: acc[64] demoted to scratch (VGPR_Count=36 < 64 live floats) ->
// 128 scratch ops per d-iteration. Restructure: 4 output-groups of 16 named
// accumulators; block = 64 cols x 4 groups so each wave is one group and the
// 32 weight reads per d stay wave-uniform s_loads. FLOPs and per-output
// arithmetic order unchanged (bit-identical results).
#define RC_DECL(i) float a##i = 0.f;
#define RC_FMA(i)  a##i = fmaf(wc[i], h, fmaf(wg[i], sv, a##i));
#define RC_STORE(i) O[(size_t)(i) * n] = a##i * inv + Pr[(size_t)(i) * n];

__global__ void __launch_bounds__(256, 1)
k_res_conv(const float* __restrict__ pts, const float* __restrict__ s,
           const float* __restrict__ wcT, const float* __restrict__ wgT,
           float* __restrict__ out, int n){
    int j = blockIdx.x * 64 + threadIdx.x;   // column
    int g = threadIdx.y;                     // output group (wave-uniform)
    if (j >= n) return;
    int b = blockIdx.y;
    const float* P = pts + (size_t)b * 64 * n + j;
    const float* S = s   + (size_t)b * 64 * n + j;
    RPT16(RC_DECL)
    for (int d = 0; d < 64; ++d){
        float h  = leaky(P[(size_t)d * n]);
        float sv = S[(size_t)d * n];
        const float* wc = wcT + d * 64 + g * 16;  // wave-uniform -> s_load
        const float* wg = wgT + d * 64 + g * 16;
        RPT16(RC_FMA)
    }
    const float inv = 1.0f / 9.0f;
    float* O = out + ((size_t)b * 64 + g * 16) * n + j;
    const float* Pr = P + (size_t)(g * 16) * n;
    RPT16(RC_STORE)
}

// ---------------- last layer: leaky -> 1x1 conv to 1 channel ----------------
__global__ void k_final(const float* __restrict__ pts, const float* __restrict__ wl,
                        float* __restrict__ out){
    int t = blockIdx.x * blockDim.x + threadIdx.x;
    if (t >= 512) return;
    int b = t >> 6, m = t & 63;
    const float* P = pts + (size_t)b * 64 * 64;
    float acc = 0.f;
    for (int d = 0; d < 64; ++d) acc += wl[d] * leaky(P[d * 64 + m]);
    out[t] = acc;
}

extern "C" void kernel_launch(void* const* d_in, const int* in_sizes, int n_in,
                              void* d_out, int out_size, void* d_ws, size_t ws_size,
                              hipStream_t stream){
    const float* xyz_in  = (const float*)d_in[0];
    const float* w0      = (const float*)d_in[1];
    const float* fn_wc   = (const float*)d_in[2];
    const float* fn_wg   = (const float*)d_in[3];
    const float* res_wc  = (const float*)d_in[4];
    const float* res_wg  = (const float*)d_in[5];
    const float* w_last  = (const float*)d_in[6];
    float* out = (float*)d_out;

    char* ws = (char*)d_ws;
    size_t off = 0;
    auto alloc = [&](size_t bytes) -> char* {
        char* p = ws + off;
        off = (off + bytes + 255) & ~(size_t)255;
        return p;
    };
    float* wT_fnc = (float*)alloc(2UL  * 4096 * 4);
    float* wT_fng = (float*)alloc(2UL  * 4096 * 4);
    float* wT_rc  = (float*)alloc(12UL * 4096 * 4);
    float* wT_rg  = (float*)alloc(12UL * 4096 * 4);
    float* pts_a  = (float*)alloc(8UL * 64 * 4096 * 4);
    float* pts_b  = (float*)alloc(8UL * 64 * 4096 * 4);
    float* s_buf  = (float*)alloc(8UL * 64 * 4096 * 4);
    int*   idx_b  = (int*)  alloc(8UL * 4096 * 8 * 4);
    float* xyz1   = (float*)alloc(8UL * 3 * 1024 * 4);
    float* xyz2   = (float*)alloc(8UL * 3 * 1024 * 4);
    int*   sidx   = (int*)  alloc(8UL * 1024 * 4);

    // transpose all weight matrices to [d][o]
    k_transpose<<<2,  256, 0, stream>>>(fn_wc,  wT_fnc);
    k_transpose<<<2,  256, 0, stream>>>(fn_wg,  wT_fng);
    k_transpose<<<12, 256, 0, stream>>>(res_wc, wT_rc);
    k_transpose<<<12, 256, 0, stream>>>(res_wg, wT_rg);

    int n = 4096;
    k_conv0<<<(8 * 64 * n) / 256, 256, 0, stream>>>(xyz_in, w0, pts_a, n);

    const float* cxyz = xyz_in;
    {
        dim3 kb((n + BKNN - 1) / BKNN, 8);
        k_knn<<<kb, BKNN, 0, stream>>>(cxyz, cxyz, n, n, idx_b);
    }
    float* pc = pts_a;
    float* pn = pts_b;
    dim3 rcb(64, 4);
    for (int j = 0; j < 2; ++j){
        dim3 g((n + 255) / 256, 64, 8);
        k_gather_sum<<<g, 256, 0, stream>>>(pc, idx_b, s_buf, n);
        dim3 g2((n + 63) / 64, 8);
        k_res_conv<<<g2, rcb, 0, stream>>>(pc, s_buf, wT_fnc + j * 4096, wT_fng + j * 4096, pn, n);
        float* t = pc; pc = pn; pn = t;
    }

    float* xyzbufs[2] = {xyz1, xyz2};
    for (int l = 0; l < 3; ++l){
        int np = n / 4;
        if (n == 4096)      k_fps16<<<8, 256, 0, stream>>>(cxyz, sidx);
        else if (n == 1024) k_fps4<<<8, 64, 0, stream>>>(cxyz, sidx);
        else                k_fps1<<<8, 64, 0, stream>>>(cxyz, sidx);

        float* nxyz = xyzbufs[l & 1];
        int tot = 8 * 3 * np;
        k_gather_xyz<<<(tot + 255) / 256, 256, 0, stream>>>(cxyz, sidx, nxyz, n, np);

        dim3 kg((np + BKNN - 1) / BKNN, 8);
        k_knn<<<kg, BKNN, 0, stream>>>(nxyz, cxyz, np, n, idx_b);

        dim3 pm((np + 255) / 256, 64, 8);
        k_pool_max<<<pm, 256, 0, stream>>>(pc, idx_b, pn, np, n);
        float* t = pc; pc = pn; pn = t;

        cxyz = nxyz; n = np;

        dim3 ks((n + BKNN - 1) / BKNN, 8);
        k_knn<<<ks, BKNN, 0, stream>>>(cxyz, cxyz, n, n, idx_b);

        for (int i = 0; i < 4; ++i){
            dim3 g((n + 255) / 256, 64, 8);
            k_gather_sum<<<g, 256, 0, stream>>>(pc, idx_b, s_buf, n);
            dim3 g2((n + 63) / 64, 8);
            k_res_conv<<<g2, rcb, 0, stream>>>(pc, s_buf, wT_rc + (l * 4 + i) * 4096,
                                               wT_rg + (l * 4 + i) * 4096, pn, n);
            t = pc; pc = pn; pn = t;
        }
    }

    k_final<<<2, 256, 0, stream>>>(pc, w_last, out);
}